// Round 6
// baseline (302.029 us; speedup 1.0000x reference)
//
#include <hip/hip_runtime.h>
#include <stdint.h>
#include <math.h>

#define DEV static __device__ __forceinline__

typedef __attribute__((ext_vector_type(8))) short bf16x8;
typedef __attribute__((ext_vector_type(4))) float f32x4;
typedef __attribute__((ext_vector_type(8))) unsigned short u16x8;
typedef __attribute__((ext_vector_type(4))) unsigned short u16x4;
typedef __attribute__((ext_vector_type(2))) unsigned int u32x2;

enum { B_ = 2, S_ = 2048, D_ = 2048, H_ = 32, HD_ = 64, N3_ = 6144, M_ = 4096 };

DEV unsigned short f2bf(float f) {
  unsigned u = __float_as_uint(f);
  u += 0x7FFFu + ((u >> 16) & 1u);
  return (unsigned short)(u >> 16);
}
DEV float bf2f(unsigned short s) { return __uint_as_float(((unsigned)s) << 16); }

DEV void load16(const void* g, void* l) {
  __builtin_amdgcn_global_load_lds((const __attribute__((address_space(1))) void*)g,
                                   (__attribute__((address_space(3))) void*)l,
                                   16, 0, 0);
}

DEV f32x4 mfma16(bf16x8 a, bf16x8 b, f32x4 c) {
  return __builtin_amdgcn_mfma_f32_16x16x32_bf16(a, b, c, 0, 0, 0);
}

// ---------------------------------------------------------------- cvt f32->bf16
__global__ __launch_bounds__(256) void cvt_bf16(const float* __restrict__ in,
                                                unsigned short* __restrict__ out, int n) {
  int i = blockIdx.x * 256 + threadIdx.x;
  if (i * 8 >= n) return;
  const float4* in4 = (const float4*)in;
  float4 a = in4[i * 2 + 0];
  float4 b = in4[i * 2 + 1];
  u16x8 o;
  o[0] = f2bf(a.x); o[1] = f2bf(a.y); o[2] = f2bf(a.z); o[3] = f2bf(a.w);
  o[4] = f2bf(b.x); o[5] = f2bf(b.y); o[6] = f2bf(b.z); o[7] = f2bf(b.w);
  *(u16x8*)(out + (size_t)i * 8) = o;
}

// ------------------------------------------- transpose f32 [K][N] -> bf16 [N][K]
__global__ __launch_bounds__(256) void transpose_bf16(const float* __restrict__ W,
                                                      unsigned short* __restrict__ Wt,
                                                      int Kg, int Ng) {
  __shared__ float tile[32][33];
  const int tn = blockIdx.x, tk = blockIdx.y;
  const int t = threadIdx.x;
  const int r = t >> 3, c4 = (t & 7) * 4;
  float4 v = *(const float4*)(W + (size_t)(tk * 32 + r) * Ng + tn * 32 + c4);
  tile[r][c4 + 0] = v.x; tile[r][c4 + 1] = v.y;
  tile[r][c4 + 2] = v.z; tile[r][c4 + 3] = v.w;
  __syncthreads();
  u16x4 o;
  o[0] = f2bf(tile[c4 + 0][r]);
  o[1] = f2bf(tile[c4 + 1][r]);
  o[2] = f2bf(tile[c4 + 2][r]);
  o[3] = f2bf(tile[c4 + 3][r]);
  *(u16x4*)(Wt + (size_t)(tn * 32 + r) * Kg + tk * 32 + c4) = o;
}

// ===================== 256x256 GEMM, BK=64, WAR-free 3-phase ==================
// A: [Mg][Kg] bf16, BT: [Ng][Kg] bf16.  512 thr = 8 waves (2M x 4N), 1 blk/CU.
// LDS 128KB: buf b at b*64KB: A 32KB | B 32KB.  Row = 128B = 8 units of 16B,
// unit u holds k8 = u ^ (row&7) (conflict-free b128 reads, linear gload dest).
// Dedicated reg sets a0/a1/b01/b23 (no WAR vs in-flight MFMA clusters);
// acc quadrants rotate per phase so consecutive clusters are independent:
//   P1: read a0,b01 ; bar ; lgkm0 ; 16 MFMA Q(0-3, 0-1)
//   P2: read a1,b23 ; bar ; lgkm0 ; 16 MFMA Q(0-3, 2-3)   [a0 x b23]
//   P3: STAGE(t+2) ; vmcnt(8) ; bar ; 32 MFMA Q(4-7, 0-3) [a1 x b01|b23]
// MODE 0: f32 out.  MODE 1: bf16 out + fused RoPE on cols < 4096.
template <int MODE>
__global__ __launch_bounds__(512, 2) void gemm256(const unsigned short* __restrict__ A,
                                                  const unsigned short* __restrict__ BT,
                                                  const float* __restrict__ bias,
                                                  void* __restrict__ Cout,
                                                  int Mg, int Ng, int Kg) {
  __shared__ __align__(16) char lds[131072];
  const int tid = threadIdx.x;
  const int lane = tid & 63, w = tid >> 6;
  const int g = (lane >> 4) & 3, l16 = lane & 15;
  const int wm = w >> 2, wn = w & 3;

  // XCD-bijective swizzle (gridDim.x % 8 == 0), tm fastest.
  const int wg = (blockIdx.x & 7) * (gridDim.x >> 3) + (blockIdx.x >> 3);
  const int nTM = Mg >> 8;
  const int tm = wg % nTM, tn = wg / nTM;
  const int rb = tm * 256, cb = tn * 256;
  const int NT = Kg >> 6;

  // ds_read byte offsets
  const int offA = (wm * 128 + l16) * 128;
  const int offB = 32768 + (wn * 64 + l16) * 128;
  const int su0 = ((0 + g) ^ (l16 & 7)) * 16;
  const int su1 = ((4 + g) ^ (l16 & 7)) * 16;

  // staging: thread tid, chunk c -> LDS row c*64 + (tid>>3), unit tid&7
  // (linear dest); global k8 = (tid&7) ^ (row&7) — c-independent.
  const int r0 = tid >> 3;
  const int u8e = ((tid & 7) ^ (r0 & 7)) * 8;
  const unsigned short* sA = A + (size_t)(rb + r0) * Kg + u8e;
  const unsigned short* sB = BT + (size_t)(cb + r0) * Kg + u8e;
  const size_t cstep = (size_t)Kg << 6;  // 64 rows
  char* const dA0 = (char*)lds + tid * 16;

  auto STAGE = [&](int t) {
    char* db = dA0 + ((t & 1) << 16);
    const size_t to = (size_t)t << 5;  // t*32 ... (BK=64 elems = 32 shorts? no)
    (void)to;
    const size_t toff = (size_t)t * 64;
#pragma unroll
    for (int c = 0; c < 4; ++c) {
      load16(sA + c * cstep + toff, db + c * 8192);
      load16(sB + c * cstep + toff, db + 32768 + c * 8192);
    }
  };

  // prologue: tiles 0,1 (16 loads); vmcnt(8) drains tile 0
  STAGE(0); STAGE(1);
  asm volatile("s_waitcnt vmcnt(8)" ::: "memory");
  __builtin_amdgcn_s_barrier();

  f32x4 acc[8][4] = {};

  for (int t = 0; t < NT; ++t) {
    const char* bs = (const char*)lds + ((t & 1) << 16);
    bf16x8 a0[4][2], a1[4][2], b01[2][2], b23[2][2];
    // -------- P1: read a0 (8) + b01 (4)
#pragma unroll
    for (int mf = 0; mf < 4; ++mf) {
      a0[mf][0] = *(const bf16x8*)(bs + offA + mf * 2048 + su0);
      a0[mf][1] = *(const bf16x8*)(bs + offA + mf * 2048 + su1);
    }
#pragma unroll
    for (int nf = 0; nf < 2; ++nf) {
      b01[nf][0] = *(const bf16x8*)(bs + offB + nf * 2048 + su0);
      b01[nf][1] = *(const bf16x8*)(bs + offB + nf * 2048 + su1);
    }
    asm volatile("s_waitcnt lgkmcnt(8)" ::: "memory");
    __builtin_amdgcn_s_barrier();
    asm volatile("s_waitcnt lgkmcnt(0)" ::: "memory");
    __builtin_amdgcn_s_setprio(1);
#pragma unroll
    for (int mf = 0; mf < 4; ++mf)
#pragma unroll
      for (int nf = 0; nf < 2; ++nf)
#pragma unroll
        for (int kh = 0; kh < 2; ++kh)
          acc[mf][nf] = mfma16(a0[mf][kh], b01[nf][kh], acc[mf][nf]);
    __builtin_amdgcn_s_setprio(0);
    __builtin_amdgcn_s_barrier();
    // -------- P2: read a1 (8) + b23 (4)
#pragma unroll
    for (int mf = 0; mf < 4; ++mf) {
      a1[mf][0] = *(const bf16x8*)(bs + offA + (mf + 4) * 2048 + su0);
      a1[mf][1] = *(const bf16x8*)(bs + offA + (mf + 4) * 2048 + su1);
    }
#pragma unroll
    for (int nf = 0; nf < 2; ++nf) {
      b23[nf][0] = *(const bf16x8*)(bs + offB + (nf + 2) * 2048 + su0);
      b23[nf][1] = *(const bf16x8*)(bs + offB + (nf + 2) * 2048 + su1);
    }
    asm volatile("s_waitcnt lgkmcnt(8)" ::: "memory");
    __builtin_amdgcn_s_barrier();
    asm volatile("s_waitcnt lgkmcnt(0)" ::: "memory");
    __builtin_amdgcn_s_setprio(1);
#pragma unroll
    for (int mf = 0; mf < 4; ++mf)
#pragma unroll
      for (int nf = 0; nf < 2; ++nf)
#pragma unroll
        for (int kh = 0; kh < 2; ++kh)
          acc[mf][nf + 2] = mfma16(a0[mf][kh], b23[nf][kh], acc[mf][nf + 2]);
    __builtin_amdgcn_s_setprio(0);
    __builtin_amdgcn_s_barrier();
    // -------- P3: stage t+2, counted vmcnt, 32 MFMA (overlaps next P1 reads)
    if (t + 2 < NT) {
      STAGE(t + 2);
      asm volatile("s_waitcnt vmcnt(8)" ::: "memory");
    } else {
      asm volatile("s_waitcnt vmcnt(0)" ::: "memory");
    }
    __builtin_amdgcn_s_barrier();
    __builtin_amdgcn_s_setprio(1);
#pragma unroll
    for (int mf = 0; mf < 4; ++mf)
#pragma unroll
      for (int nf = 0; nf < 2; ++nf)
#pragma unroll
        for (int kh = 0; kh < 2; ++kh)
          acc[mf + 4][nf] = mfma16(a1[mf][kh], b01[nf][kh], acc[mf + 4][nf]);
#pragma unroll
    for (int mf = 0; mf < 4; ++mf)
#pragma unroll
      for (int nf = 0; nf < 2; ++nf)
#pragma unroll
        for (int kh = 0; kh < 2; ++kh)
          acc[mf + 4][nf + 2] = mfma16(a1[mf][kh], b23[nf][kh], acc[mf + 4][nf + 2]);
    __builtin_amdgcn_s_setprio(0);
    __builtin_amdgcn_s_barrier();
  }

  // ---- epilogue (+ fused RoPE for MODE 1)
  const int crow0 = rb + wm * 128 + g * 4;
  const int ccol0 = cb + wn * 64 + l16;
  float bv[4];
#pragma unroll
  for (int nf = 0; nf < 4; ++nf) bv[nf] = bias[ccol0 + nf * 16];

  if (MODE == 1) {
    unsigned short* O = (unsigned short*)Cout;
    const bool dorot = (cb + wn * 64) < 4096;  // wave-uniform: q/k heads only
    const float inv = exp2f(-(float)l16 * 0.83048202372184056f);  // 10000^(-l16/16)
#pragma unroll
    for (int mf = 0; mf < 8; ++mf)
#pragma unroll
      for (int r = 0; r < 4; ++r) {
        int row = crow0 + mf * 16 + r;
        float v0 = acc[mf][0][r] + bv[0];
        float v1 = acc[mf][1][r] + bv[1];
        float v2 = acc[mf][2][r] + bv[2];
        float v3 = acc[mf][3][r] + bv[3];
        if (dorot) {
          float sn, cs;
          sincosf((float)(row & (S_ - 1)) * inv, &sn, &cs);
          float t0 = v0 * cs - v1 * sn;
          v1 = v0 * sn + v1 * cs;
          v0 = t0;
        }
        unsigned short* p = O + (size_t)row * Ng + ccol0;
        p[0] = f2bf(v0); p[16] = f2bf(v1); p[32] = f2bf(v2); p[48] = f2bf(v3);
      }
  } else {
    float* O = (float*)Cout;
#pragma unroll
    for (int mf = 0; mf < 8; ++mf)
#pragma unroll
      for (int r = 0; r < 4; ++r) {
        int row = crow0 + mf * 16 + r;
        float* p = O + (size_t)row * Ng + ccol0;
        p[0] = acc[mf][0][r] + bv[0];
        p[16] = acc[mf][1][r] + bv[1];
        p[32] = acc[mf][2][r] + bv[2];
        p[48] = acc[mf][3][r] + bv[3];
      }
  }
}

// ------------------------------------------------------------- GEMM C = A @ B^T
// 128x128 tile, BK=32, 32KB LDS, ~3 blocks/CU (m97 structure) — used for GEMM3.
DEV int xsw(int row) { return (row ^ (row >> 2)) & 3; }

template <int OUT_BF16>
__global__ __launch_bounds__(256) void gemm_bt(const unsigned short* __restrict__ A,
                                               const unsigned short* __restrict__ BT,
                                               const float* __restrict__ bias,
                                               void* __restrict__ Cout,
                                               int Mg, int Ng, int Kg) {
  __shared__ __align__(16) unsigned short lA[128 * 32];
  __shared__ __align__(16) unsigned short lB[128 * 32];
  const int tid = threadIdx.x;
  const int lane = tid & 63, wv = tid >> 6;
  const int g = lane >> 4, l16 = lane & 15;
  const int wr = wv >> 1, wc = wv & 1;
  const int rb = blockIdx.x * 128, cb = blockIdx.y * 128;

  f32x4 acc[4][4] = {};

  for (int k0 = 0; k0 < Kg; k0 += 32) {
    __syncthreads();
#pragma unroll
    for (int c = 0; c < 2; ++c) {
      int p = c * 256 + tid;
      int row = p >> 2;
      int k8l = (p & 3) ^ xsw(row);
      load16(A + (size_t)(rb + row) * Kg + k0 + 8 * k8l, (char*)lA + p * 16);
      load16(BT + (size_t)(cb + row) * Kg + k0 + 8 * k8l, (char*)lB + p * 16);
    }
    __syncthreads();
    bf16x8 af[4], bfr[4];
#pragma unroll
    for (int m = 0; m < 4; ++m) {
      int row = wr * 64 + m * 16 + l16;
      af[m] = *(const bf16x8*)((const char*)lA + (size_t)(row * 4 + (g ^ xsw(row))) * 16);
    }
#pragma unroll
    for (int n = 0; n < 4; ++n) {
      int row = wc * 64 + n * 16 + l16;
      bfr[n] = *(const bf16x8*)((const char*)lB + (size_t)(row * 4 + (g ^ xsw(row))) * 16);
    }
#pragma unroll
    for (int m = 0; m < 4; ++m)
#pragma unroll
      for (int n = 0; n < 4; ++n)
        acc[m][n] = mfma16(af[m], bfr[n], acc[m][n]);
  }

#pragma unroll
  for (int m = 0; m < 4; ++m)
#pragma unroll
    for (int n = 0; n < 4; ++n)
#pragma unroll
      for (int r = 0; r < 4; ++r) {
        int row = rb + wr * 64 + m * 16 + g * 4 + r;
        int col = cb + wc * 64 + n * 16 + l16;
        float v = acc[m][n][r] + bias[col];
        if (OUT_BF16)
          ((unsigned short*)Cout)[(size_t)row * Ng + col] = f2bf(v);
        else
          ((float*)Cout)[(size_t)row * Ng + col] = v;
      }
}

// ------------------------------------------------- V transpose -> [B,H,64,S]
__global__ __launch_bounds__(256) void vtrans(const unsigned short* __restrict__ qkv,
                                              unsigned short* __restrict__ vt) {
  __shared__ unsigned short tile[64][72];
  const int s0 = blockIdx.x * 64;
  const int bh = blockIdx.y;
  const int b = bh >> 5, h = bh & 31;
  const int t = threadIdx.x;
#pragma unroll
  for (int c = 0; c < 2; ++c) {
    int sl = (c * 256 + t) >> 3, d8 = t & 7;
    u16x8 v = *(const u16x8*)(qkv + (size_t)(b * S_ + s0 + sl) * N3_ + 4096 + h * 64 + d8 * 8);
    *(u16x8*)(&tile[sl][d8 * 8]) = v;
  }
  __syncthreads();
#pragma unroll
  for (int c = 0; c < 2; ++c) {
    int dl = (c * 256 + t) >> 3, s8 = t & 7;
    u16x8 o;
#pragma unroll
    for (int j = 0; j < 8; ++j) o[j] = tile[s8 * 8 + j][dl];
    *(u16x8*)(vt + (size_t)(bh * 64 + dl) * S_ + s0 + s8 * 8) = o;
  }
}

// ----------------------------------------------------------- flash attention
DEV void stage_kv(const unsigned short* __restrict__ qkv,
                  const unsigned short* __restrict__ vt,
                  unsigned char* lds, int bS, int bh64, int hoff, int kvb, int buf, int tid) {
#pragma unroll
  for (int c = 0; c < 2; ++c) {
    int p = c * 256 + tid;
    int row = p >> 3, k8 = (p & 7) ^ (row & 7);
    load16(qkv + (size_t)(bS + kvb + row) * N3_ + 2048 + hoff + 8 * k8,
           lds + buf * 8192 + p * 16);
    load16(vt + (size_t)(bh64 + row) * S_ + kvb + 8 * k8,
           lds + 16384 + buf * 8192 + p * 16);
  }
}

__global__ __launch_bounds__(256, 3) void attn_kernel(const unsigned short* __restrict__ qkv,
                                                      const unsigned short* __restrict__ vt,
                                                      unsigned short* __restrict__ ao) {
  __shared__ __align__(16) unsigned char lds[49152];
  const int tid = threadIdx.x;
  const int lane = tid & 63, wv = tid >> 6;
  const int g = lane >> 4, l16 = lane & 15;
  const int bid = blockIdx.x;
  const int qi = 15 - (bid >> 6);
  const int t6 = bid & 63;
  const int bh = ((t6 & 7) << 3) | (t6 >> 3);
  const int b = bh >> 5, h = bh & 31;
  const int qbase = qi * 128;
  const int srow0 = qbase + wv * 32;
  const int bS = b * S_, bh64 = bh * 64, hoff = h * 64;

  bf16x8 qf[2][2];
#pragma unroll
  for (int m = 0; m < 2; ++m)
#pragma unroll
    for (int kt = 0; kt < 2; ++kt)
      qf[m][kt] = *(const bf16x8*)(qkv + (size_t)(bS + srow0 + m * 16 + l16) * N3_ +
                                   hoff + kt * 32 + g * 8);

  float mrun[2] = {-INFINITY, -INFINITY}, lrun[2] = {0.f, 0.f};
  f32x4 o[2][4] = {};
  unsigned char* pw = lds + 32768 + wv * 4096;

  const int nkv = (qbase + 128) >> 6;
  stage_kv(qkv, vt, lds, bS, bh64, hoff, 0, 0, tid);
  __syncthreads();

  for (int kb = 0; kb < nkv; ++kb) {
    const int cur = kb & 1;
    if (kb + 1 < nkv) stage_kv(qkv, vt, lds, bS, bh64, hoff, (kb + 1) << 6, cur ^ 1, tid);
    const int kvb = kb << 6;
    if (kvb <= srow0 + 31) {
      const unsigned char* kbuf = lds + cur * 8192;
      const unsigned char* vbuf = lds + 16384 + cur * 8192;

      f32x4 sc[2][4];
#pragma unroll
      for (int n = 0; n < 4; ++n) {
        int row = n * 16 + l16;
        bf16x8 kf0 = *(const bf16x8*)(kbuf + (row * 8 + ((g + 0) ^ (row & 7))) * 16);
        bf16x8 kf1 = *(const bf16x8*)(kbuf + (row * 8 + ((g + 4) ^ (row & 7))) * 16);
#pragma unroll
        for (int m = 0; m < 2; ++m) {
          f32x4 z = {};
          z = mfma16(kf0, qf[m][0], z);
          z = mfma16(kf1, qf[m][1], z);
          sc[m][n] = z;
        }
      }

      const bool boundary = (kvb + 63 > srow0);
#pragma unroll
      for (int m = 0; m < 2; ++m) {
        const int qrow = srow0 + m * 16 + l16;
        if (boundary) {
#pragma unroll
          for (int n = 0; n < 4; ++n)
#pragma unroll
            for (int r = 0; r < 4; ++r) {
              int k = kvb + n * 16 + g * 4 + r;
              if (k > qrow) sc[m][n][r] = -INFINITY;
            }
        }
        float mx = fmaxf(fmaxf(sc[m][0][0], sc[m][0][1]), fmaxf(sc[m][0][2], sc[m][0][3]));
#pragma unroll
        for (int n = 1; n < 4; ++n)
          mx = fmaxf(mx, fmaxf(fmaxf(sc[m][n][0], sc[m][n][1]), fmaxf(sc[m][n][2], sc[m][n][3])));
        mx = fmaxf(mx, __shfl_xor(mx, 16));
        mx = fmaxf(mx, __shfl_xor(mx, 32));
        float pm = mx * 0.125f;
        if (!__all(pm <= mrun[m] + 8.0f)) {
          float mn = fmaxf(mrun[m], pm);
          float al = exp2f((mrun[m] - mn) * 1.44269504f);
          mrun[m] = mn; lrun[m] *= al;
#pragma unroll
          for (int d = 0; d < 4; ++d) o[m][d] *= al;
        }
        const float mt = mrun[m] * 1.44269504f;
        float p[4][4]; float rs = 0.f;
#pragma unroll
        for (int n = 0; n < 4; ++n)
#pragma unroll
          for (int r = 0; r < 4; ++r) {
            p[n][r] = exp2f(fmaf(sc[m][n][r], 0.18033688011112042f, -mt));
            rs += p[n][r];
          }
        rs += __shfl_xor(rs, 16);
        rs += __shfl_xor(rs, 32);
        lrun[m] += rs;
#pragma unroll
        for (int n = 0; n < 4; ++n) {
          unsigned lo, hi;
          asm("v_cvt_pk_bf16_f32 %0, %1, %2" : "=v"(lo) : "v"(p[n][0]), "v"(p[n][1]));
          asm("v_cvt_pk_bf16_f32 %0, %1, %2" : "=v"(hi) : "v"(p[n][2]), "v"(p[n][3]));
          int su = (n * 4 + g) ^ ((l16 & 7) << 1);
          u32x2 wq; wq[0] = lo; wq[1] = hi;
          *(u32x2*)(pw + ((m * 16 + l16) * 16 + su) * 8) = wq;
        }
      }

      bf16x8 pf[2][2];
#pragma unroll
      for (int m = 0; m < 2; ++m)
#pragma unroll
        for (int kt = 0; kt < 2; ++kt) {
          int su = (kt * 8 + g * 2) ^ ((l16 & 7) << 1);
          pf[m][kt] = *(const bf16x8*)(pw + ((m * 16 + l16) * 16 + su) * 8);
        }
#pragma unroll
      for (int dblk = 0; dblk < 4; ++dblk) {
        int row = dblk * 16 + l16;
        bf16x8 vf0 = *(const bf16x8*)(vbuf + (row * 8 + ((g + 0) ^ (row & 7))) * 16);
        bf16x8 vf1 = *(const bf16x8*)(vbuf + (row * 8 + ((g + 4) ^ (row & 7))) * 16);
#pragma unroll
        for (int m = 0; m < 2; ++m) {
          o[m][dblk] = mfma16(vf0, pf[m][0], o[m][dblk]);
          o[m][dblk] = mfma16(vf1, pf[m][1], o[m][dblk]);
        }
      }
    }
    __syncthreads();
  }

#pragma unroll
  for (int m = 0; m < 2; ++m) {
    float inv = 1.0f / lrun[m];
    int q = srow0 + m * 16 + l16;
#pragma unroll
    for (int dblk = 0; dblk < 4; ++dblk) {
      u16x4 ov;
#pragma unroll
      for (int r = 0; r < 4; ++r) ov[r] = f2bf(o[m][dblk][r] * inv);
      *(u16x4*)(ao + (size_t)(bS + q) * D_ + hoff + dblk * 16 + g * 4) = ov;
    }
  }
}

// ---------------------------------------------------------------------- launch
extern "C" void kernel_launch(void* const* d_in, const int* in_sizes, int n_in,
                              void* d_out, int out_size, void* d_ws, size_t ws_size,
                              hipStream_t stream) {
  const float* x = (const float*)d_in[0];
  const float* Wqkv = (const float*)d_in[1];
  const float* bqkv = (const float*)d_in[2];
  const float* Wout = (const float*)d_in[3];
  const float* bout = (const float*)d_in[4];
  float* out = (float*)d_out;

  char* ws = (char*)d_ws;
  unsigned short* Xb = (unsigned short*)(ws + 0);                  // 16 MiB (reused as AO)
  unsigned short* Wqkvt = (unsigned short*)(ws + 16777216);        // 24 MiB
  unsigned short* Woutt = (unsigned short*)(ws + 41943040);        // 8 MiB
  unsigned short* QKVb = (unsigned short*)(ws + 50331648);         // 48 MiB
  unsigned short* Vt = (unsigned short*)(ws + 100663296);          // 16 MiB
  unsigned short* AO = Xb;  // Xb is dead after gemm1

  cvt_bf16<<<4096, 256, 0, stream>>>(x, Xb, M_ * D_);
  transpose_bf16<<<dim3(192, 64), 256, 0, stream>>>(Wqkv, Wqkvt, 2048, 6144);
  transpose_bf16<<<dim3(64, 64), 256, 0, stream>>>(Wout, Woutt, 2048, 2048);
  gemm256<1><<<384, 512, 0, stream>>>(Xb, Wqkvt, bqkv, QKVb, M_, N3_, D_);
  vtrans<<<dim3(32, 64), 256, 0, stream>>>(QKVb, Vt);
  attn_kernel<<<1024, 256, 0, stream>>>(QKVb, Vt, AO);
  gemm_bt<0><<<dim3(32, 16), 256, 0, stream>>>(AO, Woutt, bout, out, M_, D_, D_);
}

// Round 7
// 297.182 us; speedup vs baseline: 1.0163x; 1.0163x over previous
//
#include <hip/hip_runtime.h>
#include <stdint.h>
#include <math.h>

#define DEV static __device__ __forceinline__

typedef __attribute__((ext_vector_type(8))) short bf16x8;
typedef __attribute__((ext_vector_type(4))) float f32x4;
typedef __attribute__((ext_vector_type(8))) unsigned short u16x8;
typedef __attribute__((ext_vector_type(4))) unsigned short u16x4;
typedef __attribute__((ext_vector_type(2))) unsigned int u32x2;

enum { B_ = 2, S_ = 2048, D_ = 2048, H_ = 32, HD_ = 64, N3_ = 6144, M_ = 4096 };

DEV unsigned short f2bf(float f) {
  unsigned u = __float_as_uint(f);
  u += 0x7FFFu + ((u >> 16) & 1u);
  return (unsigned short)(u >> 16);
}
DEV float bf2f(unsigned short s) { return __uint_as_float(((unsigned)s) << 16); }

DEV void load16(const void* g, void* l) {
  __builtin_amdgcn_global_load_lds((const __attribute__((address_space(1))) void*)g,
                                   (__attribute__((address_space(3))) void*)l,
                                   16, 0, 0);
}

DEV f32x4 mfma16(bf16x8 a, bf16x8 b, f32x4 c) {
  return __builtin_amdgcn_mfma_f32_16x16x32_bf16(a, b, c, 0, 0, 0);
}

// ---------------------------------------------------------------- cvt f32->bf16
__global__ __launch_bounds__(256) void cvt_bf16(const float* __restrict__ in,
                                                unsigned short* __restrict__ out, int n) {
  int i = blockIdx.x * 256 + threadIdx.x;
  if (i * 8 >= n) return;
  const float4* in4 = (const float4*)in;
  float4 a = in4[i * 2 + 0];
  float4 b = in4[i * 2 + 1];
  u16x8 o;
  o[0] = f2bf(a.x); o[1] = f2bf(a.y); o[2] = f2bf(a.z); o[3] = f2bf(a.w);
  o[4] = f2bf(b.x); o[5] = f2bf(b.y); o[6] = f2bf(b.z); o[7] = f2bf(b.w);
  *(u16x8*)(out + (size_t)i * 8) = o;
}

// ------------------------------------------- transpose f32 [K][N] -> bf16 [N][K]
__global__ __launch_bounds__(256) void transpose_bf16(const float* __restrict__ W,
                                                      unsigned short* __restrict__ Wt,
                                                      int Kg, int Ng) {
  __shared__ float tile[32][33];
  const int tn = blockIdx.x, tk = blockIdx.y;
  const int t = threadIdx.x;
  const int r = t >> 3, c4 = (t & 7) * 4;
  float4 v = *(const float4*)(W + (size_t)(tk * 32 + r) * Ng + tn * 32 + c4);
  tile[r][c4 + 0] = v.x; tile[r][c4 + 1] = v.y;
  tile[r][c4 + 2] = v.z; tile[r][c4 + 3] = v.w;
  __syncthreads();
  u16x4 o;
  o[0] = f2bf(tile[c4 + 0][r]);
  o[1] = f2bf(tile[c4 + 1][r]);
  o[2] = f2bf(tile[c4 + 2][r]);
  o[3] = f2bf(tile[c4 + 3][r]);
  *(u16x4*)(Wt + (size_t)(tn * 32 + r) * Kg + tk * 32 + c4) = o;
}

// ------------------------------------------------------------- GEMM C = A @ B^T
// 128x128 tile, BK=32, 32KB LDS, ~2.5 blocks/CU (m97 structure).
// MODE 0: f32 out.  MODE 1: bf16 out + fused RoPE on cols < 4096
// (wave's 64-col span = one head; acc n=0/n=1 are the rotary pair (d, d+16)).
DEV int xsw(int row) { return (row ^ (row >> 2)) & 3; }

template <int MODE>
__global__ __launch_bounds__(256) void gemm_bt(const unsigned short* __restrict__ A,
                                               const unsigned short* __restrict__ BT,
                                               const float* __restrict__ bias,
                                               void* __restrict__ Cout,
                                               int Mg, int Ng, int Kg) {
  __shared__ __align__(16) unsigned short lA[128 * 32];
  __shared__ __align__(16) unsigned short lB[128 * 32];
  const int tid = threadIdx.x;
  const int lane = tid & 63, wv = tid >> 6;
  const int g = lane >> 4, l16 = lane & 15;
  const int wr = wv >> 1, wc = wv & 1;
  const int rb = blockIdx.x * 128, cb = blockIdx.y * 128;

  f32x4 acc[4][4] = {};

  for (int k0 = 0; k0 < Kg; k0 += 32) {
    __syncthreads();
#pragma unroll
    for (int c = 0; c < 2; ++c) {
      int p = c * 256 + tid;
      int row = p >> 2;
      int k8l = (p & 3) ^ xsw(row);
      load16(A + (size_t)(rb + row) * Kg + k0 + 8 * k8l, (char*)lA + p * 16);
      load16(BT + (size_t)(cb + row) * Kg + k0 + 8 * k8l, (char*)lB + p * 16);
    }
    __syncthreads();
    bf16x8 af[4], bfr[4];
#pragma unroll
    for (int m = 0; m < 4; ++m) {
      int row = wr * 64 + m * 16 + l16;
      af[m] = *(const bf16x8*)((const char*)lA + (size_t)(row * 4 + (g ^ xsw(row))) * 16);
    }
#pragma unroll
    for (int n = 0; n < 4; ++n) {
      int row = wc * 64 + n * 16 + l16;
      bfr[n] = *(const bf16x8*)((const char*)lB + (size_t)(row * 4 + (g ^ xsw(row))) * 16);
    }
#pragma unroll
    for (int m = 0; m < 4; ++m)
#pragma unroll
      for (int n = 0; n < 4; ++n)
        acc[m][n] = mfma16(af[m], bfr[n], acc[m][n]);
  }

  const int ccol0 = cb + wc * 64 + l16;
  float bv[4];
#pragma unroll
  for (int n = 0; n < 4; ++n) bv[n] = bias[ccol0 + n * 16];

  if (MODE == 1) {
    unsigned short* O = (unsigned short*)Cout;
    const bool dorot = (cb + wc * 64) < 4096;  // wave-uniform: q/k heads only
    const float invf = exp2f(-(float)l16 * 0.83048202372184056f);  // 10000^(-l16/16)
#pragma unroll
    for (int m = 0; m < 4; ++m)
#pragma unroll
      for (int r = 0; r < 4; ++r) {
        int row = rb + wr * 64 + m * 16 + g * 4 + r;
        float v0 = acc[m][0][r] + bv[0];
        float v1 = acc[m][1][r] + bv[1];
        float v2 = acc[m][2][r] + bv[2];
        float v3 = acc[m][3][r] + bv[3];
        if (dorot) {
          float sn, cs;
          sincosf((float)(row & (S_ - 1)) * invf, &sn, &cs);
          float t0 = v0 * cs - v1 * sn;
          v1 = v0 * sn + v1 * cs;
          v0 = t0;
        }
        unsigned short* p = O + (size_t)row * Ng + ccol0;
        p[0] = f2bf(v0); p[16] = f2bf(v1); p[32] = f2bf(v2); p[48] = f2bf(v3);
      }
  } else {
    float* O = (float*)Cout;
#pragma unroll
    for (int m = 0; m < 4; ++m)
#pragma unroll
      for (int r = 0; r < 4; ++r) {
        int row = rb + wr * 64 + m * 16 + g * 4 + r;
        float* p = O + (size_t)row * Ng + ccol0;
        p[0] = acc[m][0][r] + bv[0];
        p[16] = acc[m][1][r] + bv[1];
        p[32] = acc[m][2][r] + bv[2];
        p[48] = acc[m][3][r] + bv[3];
      }
  }
}

// ------------------------------------------------- V transpose -> [B,H,64,S]
__global__ __launch_bounds__(256) void vtrans(const unsigned short* __restrict__ qkv,
                                              unsigned short* __restrict__ vt) {
  __shared__ unsigned short tile[64][72];
  const int s0 = blockIdx.x * 64;
  const int bh = blockIdx.y;
  const int b = bh >> 5, h = bh & 31;
  const int t = threadIdx.x;
#pragma unroll
  for (int c = 0; c < 2; ++c) {
    int sl = (c * 256 + t) >> 3, d8 = t & 7;
    u16x8 v = *(const u16x8*)(qkv + (size_t)(b * S_ + s0 + sl) * N3_ + 4096 + h * 64 + d8 * 8);
    *(u16x8*)(&tile[sl][d8 * 8]) = v;
  }
  __syncthreads();
#pragma unroll
  for (int c = 0; c < 2; ++c) {
    int dl = (c * 256 + t) >> 3, s8 = t & 7;
    u16x8 o;
#pragma unroll
    for (int j = 0; j < 8; ++j) o[j] = tile[s8 * 8 + j][dl];
    *(u16x8*)(vt + (size_t)(bh * 64 + dl) * S_ + s0 + s8 * 8) = o;
  }
}

// ----------------------------------------------------------- flash attention
DEV void stage_kv(const unsigned short* __restrict__ qkv,
                  const unsigned short* __restrict__ vt,
                  unsigned char* lds, int bS, int bh64, int hoff, int kvb, int buf, int tid) {
#pragma unroll
  for (int c = 0; c < 2; ++c) {
    int p = c * 256 + tid;
    int row = p >> 3, k8 = (p & 7) ^ (row & 7);
    load16(qkv + (size_t)(bS + kvb + row) * N3_ + 2048 + hoff + 8 * k8,
           lds + buf * 8192 + p * 16);
    load16(vt + (size_t)(bh64 + row) * S_ + kvb + 8 * k8,
           lds + 16384 + buf * 8192 + p * 16);
  }
}

__global__ __launch_bounds__(256, 3) void attn_kernel(const unsigned short* __restrict__ qkv,
                                                      const unsigned short* __restrict__ vt,
                                                      unsigned short* __restrict__ ao) {
  __shared__ __align__(16) unsigned char lds[49152];
  const int tid = threadIdx.x;
  const int lane = tid & 63, wv = tid >> 6;
  const int g = lane >> 4, l16 = lane & 15;
  const int bid = blockIdx.x;
  const int qi = 15 - (bid >> 6);
  const int t6 = bid & 63;
  const int bh = ((t6 & 7) << 3) | (t6 >> 3);
  const int b = bh >> 5, h = bh & 31;
  const int qbase = qi * 128;
  const int srow0 = qbase + wv * 32;
  const int bS = b * S_, bh64 = bh * 64, hoff = h * 64;

  bf16x8 qf[2][2];
#pragma unroll
  for (int m = 0; m < 2; ++m)
#pragma unroll
    for (int kt = 0; kt < 2; ++kt)
      qf[m][kt] = *(const bf16x8*)(qkv + (size_t)(bS + srow0 + m * 16 + l16) * N3_ +
                                   hoff + kt * 32 + g * 8);

  float mrun[2] = {-INFINITY, -INFINITY}, lrun[2] = {0.f, 0.f};
  f32x4 o[2][4] = {};
  unsigned char* pw = lds + 32768 + wv * 4096;

  const int nkv = (qbase + 128) >> 6;
  stage_kv(qkv, vt, lds, bS, bh64, hoff, 0, 0, tid);
  __syncthreads();

  for (int kb = 0; kb < nkv; ++kb) {
    const int cur = kb & 1;
    if (kb + 1 < nkv) stage_kv(qkv, vt, lds, bS, bh64, hoff, (kb + 1) << 6, cur ^ 1, tid);
    const int kvb = kb << 6;
    if (kvb <= srow0 + 31) {
      const unsigned char* kbuf = lds + cur * 8192;
      const unsigned char* vbuf = lds + 16384 + cur * 8192;

      f32x4 sc[2][4];
#pragma unroll
      for (int n = 0; n < 4; ++n) {
        int row = n * 16 + l16;
        bf16x8 kf0 = *(const bf16x8*)(kbuf + (row * 8 + ((g + 0) ^ (row & 7))) * 16);
        bf16x8 kf1 = *(const bf16x8*)(kbuf + (row * 8 + ((g + 4) ^ (row & 7))) * 16);
#pragma unroll
        for (int m = 0; m < 2; ++m) {
          f32x4 z = {};
          z = mfma16(kf0, qf[m][0], z);
          z = mfma16(kf1, qf[m][1], z);
          sc[m][n] = z;
        }
      }

      const bool boundary = (kvb + 63 > srow0);
#pragma unroll
      for (int m = 0; m < 2; ++m) {
        const int qrow = srow0 + m * 16 + l16;
        if (boundary) {
#pragma unroll
          for (int n = 0; n < 4; ++n)
#pragma unroll
            for (int r = 0; r < 4; ++r) {
              int k = kvb + n * 16 + g * 4 + r;
              if (k > qrow) sc[m][n][r] = -INFINITY;
            }
        }
        float mx = fmaxf(fmaxf(sc[m][0][0], sc[m][0][1]), fmaxf(sc[m][0][2], sc[m][0][3]));
#pragma unroll
        for (int n = 1; n < 4; ++n)
          mx = fmaxf(mx, fmaxf(fmaxf(sc[m][n][0], sc[m][n][1]), fmaxf(sc[m][n][2], sc[m][n][3])));
        mx = fmaxf(mx, __shfl_xor(mx, 16));
        mx = fmaxf(mx, __shfl_xor(mx, 32));
        float pm = mx * 0.125f;
        if (!__all(pm <= mrun[m] + 8.0f)) {
          float mn = fmaxf(mrun[m], pm);
          float al = exp2f((mrun[m] - mn) * 1.44269504f);
          mrun[m] = mn; lrun[m] *= al;
#pragma unroll
          for (int d = 0; d < 4; ++d) o[m][d] *= al;
        }
        const float mt = mrun[m] * 1.44269504f;
        float p[4][4]; float rs = 0.f;
#pragma unroll
        for (int n = 0; n < 4; ++n)
#pragma unroll
          for (int r = 0; r < 4; ++r) {
            p[n][r] = exp2f(fmaf(sc[m][n][r], 0.18033688011112042f, -mt));
            rs += p[n][r];
          }
        rs += __shfl_xor(rs, 16);
        rs += __shfl_xor(rs, 32);
        lrun[m] += rs;
#pragma unroll
        for (int n = 0; n < 4; ++n) {
          unsigned lo, hi;
          asm("v_cvt_pk_bf16_f32 %0, %1, %2" : "=v"(lo) : "v"(p[n][0]), "v"(p[n][1]));
          asm("v_cvt_pk_bf16_f32 %0, %1, %2" : "=v"(hi) : "v"(p[n][2]), "v"(p[n][3]));
          int su = (n * 4 + g) ^ ((l16 & 7) << 1);
          u32x2 wq; wq[0] = lo; wq[1] = hi;
          *(u32x2*)(pw + ((m * 16 + l16) * 16 + su) * 8) = wq;
        }
      }

      bf16x8 pf[2][2];
#pragma unroll
      for (int m = 0; m < 2; ++m)
#pragma unroll
        for (int kt = 0; kt < 2; ++kt) {
          int su = (kt * 8 + g * 2) ^ ((l16 & 7) << 1);
          pf[m][kt] = *(const bf16x8*)(pw + ((m * 16 + l16) * 16 + su) * 8);
        }
#pragma unroll
      for (int dblk = 0; dblk < 4; ++dblk) {
        int row = dblk * 16 + l16;
        bf16x8 vf0 = *(const bf16x8*)(vbuf + (row * 8 + ((g + 0) ^ (row & 7))) * 16);
        bf16x8 vf1 = *(const bf16x8*)(vbuf + (row * 8 + ((g + 4) ^ (row & 7))) * 16);
#pragma unroll
        for (int m = 0; m < 2; ++m) {
          o[m][dblk] = mfma16(vf0, pf[m][0], o[m][dblk]);
          o[m][dblk] = mfma16(vf1, pf[m][1], o[m][dblk]);
        }
      }
    }
    __syncthreads();
  }

#pragma unroll
  for (int m = 0; m < 2; ++m) {
    float inv = 1.0f / lrun[m];
    int q = srow0 + m * 16 + l16;
#pragma unroll
    for (int dblk = 0; dblk < 4; ++dblk) {
      u16x4 ov;
#pragma unroll
      for (int r = 0; r < 4; ++r) ov[r] = f2bf(o[m][dblk][r] * inv);
      *(u16x4*)(ao + (size_t)(bS + q) * D_ + hoff + dblk * 16 + g * 4) = ov;
    }
  }
}

// ---------------------------------------------------------------------- launch
extern "C" void kernel_launch(void* const* d_in, const int* in_sizes, int n_in,
                              void* d_out, int out_size, void* d_ws, size_t ws_size,
                              hipStream_t stream) {
  const float* x = (const float*)d_in[0];
  const float* Wqkv = (const float*)d_in[1];
  const float* bqkv = (const float*)d_in[2];
  const float* Wout = (const float*)d_in[3];
  const float* bout = (const float*)d_in[4];
  float* out = (float*)d_out;

  char* ws = (char*)d_ws;
  unsigned short* Xb = (unsigned short*)(ws + 0);                  // 16 MiB (reused as AO)
  unsigned short* Wqkvt = (unsigned short*)(ws + 16777216);        // 24 MiB
  unsigned short* Woutt = (unsigned short*)(ws + 41943040);        // 8 MiB
  unsigned short* QKVb = (unsigned short*)(ws + 50331648);         // 48 MiB
  unsigned short* Vt = (unsigned short*)(ws + 100663296);          // 16 MiB
  unsigned short* AO = Xb;  // Xb is dead after gemm1

  cvt_bf16<<<4096, 256, 0, stream>>>(x, Xb, M_ * D_);
  transpose_bf16<<<dim3(192, 64), 256, 0, stream>>>(Wqkv, Wqkvt, 2048, 6144);
  transpose_bf16<<<dim3(64, 64), 256, 0, stream>>>(Wout, Woutt, 2048, 2048);
  gemm_bt<1><<<dim3(32, 48), 256, 0, stream>>>(Xb, Wqkvt, bqkv, QKVb, M_, N3_, D_);
  vtrans<<<dim3(32, 64), 256, 0, stream>>>(QKVb, Vt);
  attn_kernel<<<1024, 256, 0, stream>>>(QKVb, Vt, AO);
  gemm_bt<0><<<dim3(32, 16), 256, 0, stream>>>(AO, Woutt, bout, out, M_, D_, D_);
}

// Round 8
// 290.080 us; speedup vs baseline: 1.0412x; 1.0245x over previous
//
#include <hip/hip_runtime.h>
#include <stdint.h>
#include <math.h>

#define DEV static __device__ __forceinline__

typedef __attribute__((ext_vector_type(8))) short bf16x8;
typedef __attribute__((ext_vector_type(4))) float f32x4;
typedef __attribute__((ext_vector_type(8))) unsigned short u16x8;
typedef __attribute__((ext_vector_type(4))) unsigned short u16x4;
typedef __attribute__((ext_vector_type(2))) unsigned int u32x2;

enum { B_ = 2, S_ = 2048, D_ = 2048, H_ = 32, HD_ = 64, N3_ = 6144, M_ = 4096 };

DEV unsigned short f2bf(float f) {
  unsigned u = __float_as_uint(f);
  u += 0x7FFFu + ((u >> 16) & 1u);
  return (unsigned short)(u >> 16);
}
DEV float bf2f(unsigned short s) { return __uint_as_float(((unsigned)s) << 16); }

DEV void load16(const void* g, void* l) {
  __builtin_amdgcn_global_load_lds((const __attribute__((address_space(1))) void*)g,
                                   (__attribute__((address_space(3))) void*)l,
                                   16, 0, 0);
}

DEV f32x4 mfma16(bf16x8 a, bf16x8 b, f32x4 c) {
  return __builtin_amdgcn_mfma_f32_16x16x32_bf16(a, b, c, 0, 0, 0);
}

// ---------------------------------------------------------------- cvt f32->bf16
__global__ __launch_bounds__(256) void cvt_bf16(const float* __restrict__ in,
                                                unsigned short* __restrict__ out, int n) {
  int i = blockIdx.x * 256 + threadIdx.x;
  if (i * 8 >= n) return;
  const float4* in4 = (const float4*)in;
  float4 a = in4[i * 2 + 0];
  float4 b = in4[i * 2 + 1];
  u16x8 o;
  o[0] = f2bf(a.x); o[1] = f2bf(a.y); o[2] = f2bf(a.z); o[3] = f2bf(a.w);
  o[4] = f2bf(b.x); o[5] = f2bf(b.y); o[6] = f2bf(b.z); o[7] = f2bf(b.w);
  *(u16x8*)(out + (size_t)i * 8) = o;
}

// ------------------------------------------- transpose f32 [K][N] -> bf16 [N][K]
__global__ __launch_bounds__(256) void transpose_bf16(const float* __restrict__ W,
                                                      unsigned short* __restrict__ Wt,
                                                      int Kg, int Ng) {
  __shared__ float tile[32][33];
  const int tn = blockIdx.x, tk = blockIdx.y;
  const int t = threadIdx.x;
  const int r = t >> 3, c4 = (t & 7) * 4;
  float4 v = *(const float4*)(W + (size_t)(tk * 32 + r) * Ng + tn * 32 + c4);
  tile[r][c4 + 0] = v.x; tile[r][c4 + 1] = v.y;
  tile[r][c4 + 2] = v.z; tile[r][c4 + 3] = v.w;
  __syncthreads();
  u16x4 o;
  o[0] = f2bf(tile[c4 + 0][r]);
  o[1] = f2bf(tile[c4 + 1][r]);
  o[2] = f2bf(tile[c4 + 2][r]);
  o[3] = f2bf(tile[c4 + 3][r]);
  *(u16x4*)(Wt + (size_t)(tn * 32 + r) * Kg + tk * 32 + c4) = o;
}

// ------------------------------------------------------------- GEMM C = A @ B^T
// 128x128 tile, BK=32, 32KB LDS, ~3 blocks/CU (m97 structure).
// MODE 0: f32 out.
// MODE 1: QKV mode — bf16 out; cols <4096 (q,k): fused RoPE (fast HW trig);
//         cols >=4096 (v): written TRANSPOSED to vt[(b*32+h)*64+d][s].
DEV int xsw(int row) { return (row ^ (row >> 2)) & 3; }

template <int MODE>
__global__ __launch_bounds__(256) void gemm_bt(const unsigned short* __restrict__ A,
                                               const unsigned short* __restrict__ BT,
                                               const float* __restrict__ bias,
                                               void* __restrict__ Cout,
                                               unsigned short* __restrict__ vt,
                                               int Mg, int Ng, int Kg) {
  __shared__ __align__(16) unsigned short lA[128 * 32];
  __shared__ __align__(16) unsigned short lB[128 * 32];
  const int tid = threadIdx.x;
  const int lane = tid & 63, wv = tid >> 6;
  const int g = lane >> 4, l16 = lane & 15;
  const int wr = wv >> 1, wc = wv & 1;
  const int rb = blockIdx.x * 128, cb = blockIdx.y * 128;

  f32x4 acc[4][4] = {};

  for (int k0 = 0; k0 < Kg; k0 += 32) {
    __syncthreads();
#pragma unroll
    for (int c = 0; c < 2; ++c) {
      int p = c * 256 + tid;
      int row = p >> 2;
      int k8l = (p & 3) ^ xsw(row);
      load16(A + (size_t)(rb + row) * Kg + k0 + 8 * k8l, (char*)lA + p * 16);
      load16(BT + (size_t)(cb + row) * Kg + k0 + 8 * k8l, (char*)lB + p * 16);
    }
    __syncthreads();
    bf16x8 af[4], bfr[4];
#pragma unroll
    for (int m = 0; m < 4; ++m) {
      int row = wr * 64 + m * 16 + l16;
      af[m] = *(const bf16x8*)((const char*)lA + (size_t)(row * 4 + (g ^ xsw(row))) * 16);
    }
#pragma unroll
    for (int n = 0; n < 4; ++n) {
      int row = wc * 64 + n * 16 + l16;
      bfr[n] = *(const bf16x8*)((const char*)lB + (size_t)(row * 4 + (g ^ xsw(row))) * 16);
    }
#pragma unroll
    for (int m = 0; m < 4; ++m)
#pragma unroll
      for (int n = 0; n < 4; ++n)
        acc[m][n] = mfma16(af[m], bfr[n], acc[m][n]);
  }

  const int ccol0 = cb + wc * 64 + l16;
  float bv[4];
#pragma unroll
  for (int n = 0; n < 4; ++n) bv[n] = bias[ccol0 + n * 16];

  if (MODE == 1) {
    const int cblk = cb + wc * 64;  // wave-uniform 64-col span = one head
    if (cblk >= 4096) {
      // ---- V: write transposed to vt[(b*32+hv)*64 + d][s]
      const int hv = (cblk - 4096) >> 6;
#pragma unroll
      for (int m = 0; m < 4; ++m) {
        int row = rb + wr * 64 + m * 16 + g * 4;  // r=0..3 consecutive s
        int b = row >> 11, s0 = row & (S_ - 1);
#pragma unroll
        for (int n = 0; n < 4; ++n) {
          u16x4 ov;
#pragma unroll
          for (int r = 0; r < 4; ++r) ov[r] = f2bf(acc[m][n][r] + bv[n]);
          *(u16x4*)(vt + ((size_t)(b * 32 + hv) * 64 + n * 16 + l16) * S_ + s0) = ov;
        }
      }
    } else {
      // ---- Q/K: fused RoPE (acc n=0/n=1 are the rotary pair (d, d+16))
      unsigned short* O = (unsigned short*)Cout;
      const float invf = exp2f(-(float)l16 * 0.83048202372184056f);  // 10000^(-l16/16)
#pragma unroll
      for (int m = 0; m < 4; ++m)
#pragma unroll
        for (int r = 0; r < 4; ++r) {
          int row = rb + wr * 64 + m * 16 + g * 4 + r;
          float v0 = acc[m][0][r] + bv[0];
          float v1 = acc[m][1][r] + bv[1];
          float v2 = acc[m][2][r] + bv[2];
          float v3 = acc[m][3][r] + bv[3];
          float ang = (float)(row & (S_ - 1)) * invf;
          float sn = __sinf(ang), cs = __cosf(ang);
          float t0 = v0 * cs - v1 * sn;
          v1 = v0 * sn + v1 * cs;
          v0 = t0;
          unsigned short* p = O + (size_t)row * Ng + ccol0;
          p[0] = f2bf(v0); p[16] = f2bf(v1); p[32] = f2bf(v2); p[48] = f2bf(v3);
        }
    }
  } else {
    float* O = (float*)Cout;
#pragma unroll
    for (int m = 0; m < 4; ++m)
#pragma unroll
      for (int r = 0; r < 4; ++r) {
        int row = rb + wr * 64 + m * 16 + g * 4 + r;
        float* p = O + (size_t)row * Ng + ccol0;
        p[0] = acc[m][0][r] + bv[0];
        p[16] = acc[m][1][r] + bv[1];
        p[32] = acc[m][2][r] + bv[2];
        p[48] = acc[m][3][r] + bv[3];
      }
  }
}

// ----------------------------------------------------------- flash attention
DEV void stage_kv(const unsigned short* __restrict__ qkv,
                  const unsigned short* __restrict__ vt,
                  unsigned char* lds, int bS, int bh64, int hoff, int kvb, int buf, int tid) {
#pragma unroll
  for (int c = 0; c < 2; ++c) {
    int p = c * 256 + tid;
    int row = p >> 3, k8 = (p & 7) ^ (row & 7);
    load16(qkv + (size_t)(bS + kvb + row) * N3_ + 2048 + hoff + 8 * k8,
           lds + buf * 8192 + p * 16);
    load16(vt + (size_t)(bh64 + row) * S_ + kvb + 8 * k8,
           lds + 16384 + buf * 8192 + p * 16);
  }
}

__global__ __launch_bounds__(256, 3) void attn_kernel(const unsigned short* __restrict__ qkv,
                                                      const unsigned short* __restrict__ vt,
                                                      unsigned short* __restrict__ ao) {
  __shared__ __align__(16) unsigned char lds[49152];
  const int tid = threadIdx.x;
  const int lane = tid & 63, wv = tid >> 6;
  const int g = lane >> 4, l16 = lane & 15;
  const int bid = blockIdx.x;
  const int qi = 15 - (bid >> 6);
  const int t6 = bid & 63;
  const int bh = ((t6 & 7) << 3) | (t6 >> 3);
  const int b = bh >> 5, h = bh & 31;
  const int qbase = qi * 128;
  const int srow0 = qbase + wv * 32;
  const int bS = b * S_, bh64 = bh * 64, hoff = h * 64;

  bf16x8 qf[2][2];
#pragma unroll
  for (int m = 0; m < 2; ++m)
#pragma unroll
    for (int kt = 0; kt < 2; ++kt)
      qf[m][kt] = *(const bf16x8*)(qkv + (size_t)(bS + srow0 + m * 16 + l16) * N3_ +
                                   hoff + kt * 32 + g * 8);

  float mrun[2] = {-INFINITY, -INFINITY}, lrun[2] = {0.f, 0.f};
  f32x4 o[2][4] = {};
  unsigned char* pw = lds + 32768 + wv * 4096;

  const int nkv = (qbase + 128) >> 6;
  stage_kv(qkv, vt, lds, bS, bh64, hoff, 0, 0, tid);
  __syncthreads();

  for (int kb = 0; kb < nkv; ++kb) {
    const int cur = kb & 1;
    if (kb + 1 < nkv) stage_kv(qkv, vt, lds, bS, bh64, hoff, (kb + 1) << 6, cur ^ 1, tid);
    const int kvb = kb << 6;
    if (kvb <= srow0 + 31) {
      const unsigned char* kbuf = lds + cur * 8192;
      const unsigned char* vbuf = lds + 16384 + cur * 8192;

      f32x4 sc[2][4];
#pragma unroll
      for (int n = 0; n < 4; ++n) {
        int row = n * 16 + l16;
        bf16x8 kf0 = *(const bf16x8*)(kbuf + (row * 8 + ((g + 0) ^ (row & 7))) * 16);
        bf16x8 kf1 = *(const bf16x8*)(kbuf + (row * 8 + ((g + 4) ^ (row & 7))) * 16);
#pragma unroll
        for (int m = 0; m < 2; ++m) {
          f32x4 z = {};
          z = mfma16(kf0, qf[m][0], z);
          z = mfma16(kf1, qf[m][1], z);
          sc[m][n] = z;
        }
      }

      const bool boundary = (kvb + 63 > srow0);
#pragma unroll
      for (int m = 0; m < 2; ++m) {
        const int qrow = srow0 + m * 16 + l16;
        if (boundary) {
#pragma unroll
          for (int n = 0; n < 4; ++n)
#pragma unroll
            for (int r = 0; r < 4; ++r) {
              int k = kvb + n * 16 + g * 4 + r;
              if (k > qrow) sc[m][n][r] = -INFINITY;
            }
        }
        float mx = fmaxf(fmaxf(sc[m][0][0], sc[m][0][1]), fmaxf(sc[m][0][2], sc[m][0][3]));
#pragma unroll
        for (int n = 1; n < 4; ++n)
          mx = fmaxf(mx, fmaxf(fmaxf(sc[m][n][0], sc[m][n][1]), fmaxf(sc[m][n][2], sc[m][n][3])));
        mx = fmaxf(mx, __shfl_xor(mx, 16));
        mx = fmaxf(mx, __shfl_xor(mx, 32));
        float pm = mx * 0.125f;
        if (!__all(pm <= mrun[m] + 8.0f)) {
          float mn = fmaxf(mrun[m], pm);
          float al = exp2f((mrun[m] - mn) * 1.44269504f);
          mrun[m] = mn; lrun[m] *= al;
#pragma unroll
          for (int d = 0; d < 4; ++d) o[m][d] *= al;
        }
        const float mt = mrun[m] * 1.44269504f;
        float p[4][4]; float rs = 0.f;
#pragma unroll
        for (int n = 0; n < 4; ++n)
#pragma unroll
          for (int r = 0; r < 4; ++r) {
            p[n][r] = exp2f(fmaf(sc[m][n][r], 0.18033688011112042f, -mt));
            rs += p[n][r];
          }
        rs += __shfl_xor(rs, 16);
        rs += __shfl_xor(rs, 32);
        lrun[m] += rs;
#pragma unroll
        for (int n = 0; n < 4; ++n) {
          unsigned lo, hi;
          asm("v_cvt_pk_bf16_f32 %0, %1, %2" : "=v"(lo) : "v"(p[n][0]), "v"(p[n][1]));
          asm("v_cvt_pk_bf16_f32 %0, %1, %2" : "=v"(hi) : "v"(p[n][2]), "v"(p[n][3]));
          int su = (n * 4 + g) ^ ((l16 & 7) << 1);
          u32x2 wq; wq[0] = lo; wq[1] = hi;
          *(u32x2*)(pw + ((m * 16 + l16) * 16 + su) * 8) = wq;
        }
      }

      bf16x8 pf[2][2];
#pragma unroll
      for (int m = 0; m < 2; ++m)
#pragma unroll
        for (int kt = 0; kt < 2; ++kt) {
          int su = (kt * 8 + g * 2) ^ ((l16 & 7) << 1);
          pf[m][kt] = *(const bf16x8*)(pw + ((m * 16 + l16) * 16 + su) * 8);
        }
#pragma unroll
      for (int dblk = 0; dblk < 4; ++dblk) {
        int row = dblk * 16 + l16;
        bf16x8 vf0 = *(const bf16x8*)(vbuf + (row * 8 + ((g + 0) ^ (row & 7))) * 16);
        bf16x8 vf1 = *(const bf16x8*)(vbuf + (row * 8 + ((g + 4) ^ (row & 7))) * 16);
#pragma unroll
        for (int m = 0; m < 2; ++m) {
          o[m][dblk] = mfma16(vf0, pf[m][0], o[m][dblk]);
          o[m][dblk] = mfma16(vf1, pf[m][1], o[m][dblk]);
        }
      }
    }
    __syncthreads();
  }

#pragma unroll
  for (int m = 0; m < 2; ++m) {
    float inv = 1.0f / lrun[m];
    int q = srow0 + m * 16 + l16;
#pragma unroll
    for (int dblk = 0; dblk < 4; ++dblk) {
      u16x4 ov;
#pragma unroll
      for (int r = 0; r < 4; ++r) ov[r] = f2bf(o[m][dblk][r] * inv);
      *(u16x4*)(ao + (size_t)(bS + q) * D_ + hoff + dblk * 16 + g * 4) = ov;
    }
  }
}

// ---------------------------------------------------------------------- launch
extern "C" void kernel_launch(void* const* d_in, const int* in_sizes, int n_in,
                              void* d_out, int out_size, void* d_ws, size_t ws_size,
                              hipStream_t stream) {
  const float* x = (const float*)d_in[0];
  const float* Wqkv = (const float*)d_in[1];
  const float* bqkv = (const float*)d_in[2];
  const float* Wout = (const float*)d_in[3];
  const float* bout = (const float*)d_in[4];
  float* out = (float*)d_out;

  char* ws = (char*)d_ws;
  unsigned short* Xb = (unsigned short*)(ws + 0);                  // 16 MiB (reused as AO)
  unsigned short* Wqkvt = (unsigned short*)(ws + 16777216);        // 24 MiB
  unsigned short* Woutt = (unsigned short*)(ws + 41943040);        // 8 MiB
  unsigned short* QKVb = (unsigned short*)(ws + 50331648);         // 48 MiB
  unsigned short* Vt = (unsigned short*)(ws + 100663296);          // 16 MiB
  unsigned short* AO = Xb;  // Xb is dead after gemm1

  cvt_bf16<<<4096, 256, 0, stream>>>(x, Xb, M_ * D_);
  transpose_bf16<<<dim3(192, 64), 256, 0, stream>>>(Wqkv, Wqkvt, 2048, 6144);
  transpose_bf16<<<dim3(64, 64), 256, 0, stream>>>(Wout, Woutt, 2048, 2048);
  gemm_bt<1><<<dim3(32, 48), 256, 0, stream>>>(Xb, Wqkvt, bqkv, QKVb, Vt, M_, N3_, D_);
  attn_kernel<<<1024, 256, 0, stream>>>(QKVb, Vt, AO);
  gemm_bt<0><<<dim3(32, 16), 256, 0, stream>>>(AO, Woutt, bout, out, nullptr, M_, D_, D_);
}

// Round 9
// 265.111 us; speedup vs baseline: 1.1393x; 1.0942x over previous
//
#include <hip/hip_runtime.h>
#include <stdint.h>
#include <math.h>

#define DEV static __device__ __forceinline__

typedef __attribute__((ext_vector_type(8))) short bf16x8;
typedef __attribute__((ext_vector_type(4))) float f32x4;
typedef __attribute__((ext_vector_type(8))) unsigned short u16x8;
typedef __attribute__((ext_vector_type(4))) unsigned short u16x4;
typedef __attribute__((ext_vector_type(2))) unsigned int u32x2;

enum { B_ = 2, S_ = 2048, D_ = 2048, H_ = 32, HD_ = 64, N3_ = 6144, M_ = 4096 };

DEV unsigned short f2bf(float f) {
  unsigned u = __float_as_uint(f);
  u += 0x7FFFu + ((u >> 16) & 1u);
  return (unsigned short)(u >> 16);
}
DEV float bf2f(unsigned short s) { return __uint_as_float(((unsigned)s) << 16); }

DEV void load16(const void* g, void* l) {
  __builtin_amdgcn_global_load_lds((const __attribute__((address_space(1))) void*)g,
                                   (__attribute__((address_space(3))) void*)l,
                                   16, 0, 0);
}

DEV f32x4 mfma16(bf16x8 a, bf16x8 b, f32x4 c) {
  return __builtin_amdgcn_mfma_f32_16x16x32_bf16(a, b, c, 0, 0, 0);
}

// ---------------------------------------------------------------- cvt f32->bf16
__global__ __launch_bounds__(256) void cvt_bf16(const float* __restrict__ in,
                                                unsigned short* __restrict__ out, int n) {
  int i = blockIdx.x * 256 + threadIdx.x;
  if (i * 8 >= n) return;
  const float4* in4 = (const float4*)in;
  float4 a = in4[i * 2 + 0];
  float4 b = in4[i * 2 + 1];
  u16x8 o;
  o[0] = f2bf(a.x); o[1] = f2bf(a.y); o[2] = f2bf(a.z); o[3] = f2bf(a.w);
  o[4] = f2bf(b.x); o[5] = f2bf(b.y); o[6] = f2bf(b.z); o[7] = f2bf(b.w);
  *(u16x8*)(out + (size_t)i * 8) = o;
}

// ------------------------------------------- transpose f32 [K][N] -> bf16 [N][K]
__global__ __launch_bounds__(256) void transpose_bf16(const float* __restrict__ W,
                                                      unsigned short* __restrict__ Wt,
                                                      int Kg, int Ng) {
  __shared__ float tile[32][33];
  const int tn = blockIdx.x, tk = blockIdx.y;
  const int t = threadIdx.x;
  const int r = t >> 3, c4 = (t & 7) * 4;
  float4 v = *(const float4*)(W + (size_t)(tk * 32 + r) * Ng + tn * 32 + c4);
  tile[r][c4 + 0] = v.x; tile[r][c4 + 1] = v.y;
  tile[r][c4 + 2] = v.z; tile[r][c4 + 3] = v.w;
  __syncthreads();
  u16x4 o;
  o[0] = f2bf(tile[c4 + 0][r]);
  o[1] = f2bf(tile[c4 + 1][r]);
  o[2] = f2bf(tile[c4 + 2][r]);
  o[3] = f2bf(tile[c4 + 3][r]);
  *(u16x4*)(Wt + (size_t)(tn * 32 + r) * Kg + tk * 32 + c4) = o;
}

// ============== 256x192 QKV GEMM, BK=64, 2-phase pipelined, grid=512 ==========
// A: [4096][2048] bf16, BT: [6144][2048] bf16. 512 thr = 8 waves (2M x 4N).
// Wave tile 128 rows x 48 cols as 3 scattered 16-col groups (RoPE pairs intra-
// wave: w0{0,16,32} w1{64,80,48} w2{128,144,96} w3{112,160,176} per 192 cols).
// LDS 112KB: buf at {0,57344}: A 32KB (4 chunks of 64 rows) | B 24KB (3 chunks).
// Row=128B=8 units of 16B; unit u holds k8 = u^(row&7); linear gload dest with
// inverse-swizzled global source (rule: both-sides-or-neither).
// Region discipline: P1 reads A0{rows 0-63,128-191}+all B -> closing barrier
// legalizes P2's stage of A0/B(t+2) into current buf. A1(t+1) staged in P1 into
// the other buf. Split counted vmcnt: entry-vmcnt(7) gates A1(t); exit-vmcnt(7)
// gates A0/B(t+1). Never 0 in steady state.
__global__ __launch_bounds__(512, 2) void gemm_qkv(const unsigned short* __restrict__ A,
                                                   const unsigned short* __restrict__ BT,
                                                   const float* __restrict__ bias,
                                                   unsigned short* __restrict__ Oqk,
                                                   unsigned short* __restrict__ vt,
                                                   int Mg, int Ng, int Kg) {
  __shared__ __align__(16) char lds[114688];
  const int tid = threadIdx.x;
  const int lane = tid & 63, w = tid >> 6;
  const int g = (lane >> 4) & 3, l16 = lane & 15;
  const int wm = w >> 2, wn = w & 3;

  // XCD-bijective swizzle (512 % 8 == 0), tm fastest (B-panel L2 reuse).
  const int wg = (blockIdx.x & 7) * (gridDim.x >> 3) + (blockIdx.x >> 3);
  const int nTM = Mg >> 8;
  const int tm = wg % nTM, tn = wg / nTM;
  const int rb = tm * 256, cb = tn * 192;
  const int NT = Kg >> 6;

  // column-group table (rotary pair always at groups 0,1 when wn<3)
  int c0, c1, c2;
  if (wn == 0)      { c0 = 0;   c1 = 16;  c2 = 32;  }
  else if (wn == 1) { c0 = 64;  c1 = 80;  c2 = 48;  }
  else if (wn == 2) { c0 = 128; c1 = 144; c2 = 96;  }
  else              { c0 = 112; c1 = 160; c2 = 176; }

  const int su0 = (g ^ (l16 & 7)) * 16;
  const int su1 = ((4 + g) ^ (l16 & 7)) * 16;
  const int offA = (wm * 128 + l16) * 128;
  const int offB0 = 32768 + (c0 + l16) * 128;
  const int offB1 = 32768 + (c1 + l16) * 128;
  const int offB2 = 32768 + (c2 + l16) * 128;

  // staging maps (chunk = 64 rows; dest linear, source inverse-swizzled)
  const int r0 = tid >> 3;
  const int u8e = ((tid & 7) ^ (r0 & 7)) * 8;
  const unsigned short* sAa = A + (size_t)(rb + r0) * Kg + u8e;
  const unsigned short* sBb = BT + (size_t)(cb + r0) * Kg + u8e;
  const size_t rs64 = (size_t)Kg * 64;
  const int dstb = tid * 16;

  auto SA0 = [&](int t) { char* db = (char*)lds + ((t & 1) ? 57344 : 0);
    load16(sAa + (size_t)t * 64, db + dstb);
    load16(sAa + 2 * rs64 + (size_t)t * 64, db + 16384 + dstb); };
  auto SA1 = [&](int t) { char* db = (char*)lds + ((t & 1) ? 57344 : 0);
    load16(sAa + 1 * rs64 + (size_t)t * 64, db + 8192 + dstb);
    load16(sAa + 3 * rs64 + (size_t)t * 64, db + 24576 + dstb); };
  auto SB = [&](int t) { char* db = (char*)lds + ((t & 1) ? 57344 : 0) + 32768;
    load16(sBb + (size_t)t * 64, db + dstb);
    load16(sBb + 1 * rs64 + (size_t)t * 64, db + 8192 + dstb);
    load16(sBb + 2 * rs64 + (size_t)t * 64, db + 16384 + dstb); };

  // prologue: tile0 full (7) + tile1 {A0,B} (5); vmcnt(5) drains tile0
  SA0(0); SA1(0); SB(0); SA0(1); SB(1);
  asm volatile("s_waitcnt vmcnt(5)" ::: "memory");
  __builtin_amdgcn_s_barrier();

  f32x4 acc[8][3] = {};
  bf16x8 a[4][2], b[3][2];

  for (int t = 0; t < NT; ++t) {
    const char* bs = (const char*)lds + ((t & 1) ? 57344 : 0);
    // ---- P1: read a rows [wm*128, +64) (A0) + all 3 B groups; stage A1(t+1)
#pragma unroll
    for (int mf = 0; mf < 4; ++mf) {
      a[mf][0] = *(const bf16x8*)(bs + offA + mf * 2048 + su0);
      a[mf][1] = *(const bf16x8*)(bs + offA + mf * 2048 + su1);
    }
    b[0][0] = *(const bf16x8*)(bs + offB0 + su0);
    b[0][1] = *(const bf16x8*)(bs + offB0 + su1);
    b[1][0] = *(const bf16x8*)(bs + offB1 + su0);
    b[1][1] = *(const bf16x8*)(bs + offB1 + su1);
    b[2][0] = *(const bf16x8*)(bs + offB2 + su0);
    b[2][1] = *(const bf16x8*)(bs + offB2 + su1);
    if (t + 1 < NT) SA1(t + 1);
    asm volatile("s_waitcnt lgkmcnt(8)" ::: "memory");
    __builtin_amdgcn_s_barrier();
    asm volatile("s_waitcnt lgkmcnt(0)" ::: "memory");
    __builtin_amdgcn_s_setprio(1);
#pragma unroll
    for (int mf = 0; mf < 4; ++mf)
#pragma unroll
      for (int nf = 0; nf < 3; ++nf)
#pragma unroll
        for (int kh = 0; kh < 2; ++kh)
          acc[mf][nf] = mfma16(a[mf][kh], b[nf][kh], acc[mf][nf]);
    __builtin_amdgcn_s_setprio(0);
    __builtin_amdgcn_s_barrier();
    // ---- P2: entry vmcnt gates A1(t); read a rows +64 (A1); stage A0/B(t+2)
    if (t == NT - 1) asm volatile("s_waitcnt vmcnt(0)" ::: "memory");
    else             asm volatile("s_waitcnt vmcnt(7)" ::: "memory");
#pragma unroll
    for (int mf = 0; mf < 4; ++mf) {
      a[mf][0] = *(const bf16x8*)(bs + offA + (mf + 4) * 2048 + su0);
      a[mf][1] = *(const bf16x8*)(bs + offA + (mf + 4) * 2048 + su1);
    }
    if (t + 2 < NT) { SA0(t + 2); SB(t + 2); }
    __builtin_amdgcn_s_barrier();
    asm volatile("s_waitcnt lgkmcnt(0)" ::: "memory");
    __builtin_amdgcn_s_setprio(1);
#pragma unroll
    for (int mf = 0; mf < 4; ++mf)
#pragma unroll
      for (int nf = 0; nf < 3; ++nf)
#pragma unroll
        for (int kh = 0; kh < 2; ++kh)
          acc[mf + 4][nf] = mfma16(a[mf][kh], b[nf][kh], acc[mf + 4][nf]);
    __builtin_amdgcn_s_setprio(0);
    if (t + 2 < NT)      asm volatile("s_waitcnt vmcnt(7)" ::: "memory");
    else if (t + 1 < NT) asm volatile("s_waitcnt vmcnt(2)" ::: "memory");
    __builtin_amdgcn_s_barrier();
  }

  // ---- epilogue: fused RoPE (groups 0,1 when rotary) + V transposed store
  const int crow0 = rb + wm * 128 + g * 4;
  const float bv0 = bias[cb + c0 + l16];
  const float bv1 = bias[cb + c1 + l16];
  const float bv2 = bias[cb + c2 + l16];
  const bool rotp = (wn < 3) && (cb + c0 < 4096);
  const float invf = exp2f(-(float)l16 * 0.83048202372184056f);  // 10000^(-l16/16)

#define STOREG(NF, CG, BV) do {                                                \
    const int col0_ = cb + (CG);                                               \
    if (col0_ >= 4096) {                                                       \
      const int hv_ = (col0_ - 4096) >> 6;                                     \
      const int dd_ = (col0_ & 63) + l16;                                      \
      _Pragma("unroll")                                                        \
      for (int mf = 0; mf < 8; ++mf) {                                         \
        int rowb_ = crow0 + mf * 16;                                           \
        int bb_ = rowb_ >> 11, s0_ = rowb_ & (S_ - 1);                         \
        u16x4 ov_;                                                             \
        _Pragma("unroll")                                                      \
        for (int r = 0; r < 4; ++r) ov_[r] = f2bf(acc[mf][NF][r] + (BV));      \
        *(u16x4*)(vt + ((size_t)(bb_ * 32 + hv_) * 64 + dd_) * S_ + s0_) = ov_;\
      }                                                                        \
    } else {                                                                   \
      _Pragma("unroll")                                                        \
      for (int mf = 0; mf < 8; ++mf)                                           \
        _Pragma("unroll")                                                      \
        for (int r = 0; r < 4; ++r) {                                          \
          int row_ = crow0 + mf * 16 + r;                                      \
          Oqk[(size_t)row_ * Ng + col0_ + l16] = f2bf(acc[mf][NF][r] + (BV));  \
        }                                                                      \
    }                                                                          \
  } while (0)

  if (rotp) {
#pragma unroll
    for (int mf = 0; mf < 8; ++mf)
#pragma unroll
      for (int r = 0; r < 4; ++r) {
        int row = crow0 + mf * 16 + r;
        float v0 = acc[mf][0][r] + bv0;
        float v1 = acc[mf][1][r] + bv1;
        float ang = (float)(row & (S_ - 1)) * invf;
        float sn = __sinf(ang), cs = __cosf(ang);
        float t0 = v0 * cs - v1 * sn;
        v1 = v0 * sn + v1 * cs;
        unsigned short* p = Oqk + (size_t)row * Ng;
        p[cb + c0 + l16] = f2bf(t0);
        p[cb + c1 + l16] = f2bf(v1);
      }
  } else {
    STOREG(0, c0, bv0);
    STOREG(1, c1, bv1);
  }
  STOREG(2, c2, bv2);
#undef STOREG
}

// ------------------------------------------------------------- GEMM C = A @ B^T
// 128x128 tile, BK=32, 32KB LDS, ~3 blocks/CU (m97 structure) — GEMM3.
DEV int xsw(int row) { return (row ^ (row >> 2)) & 3; }

__global__ __launch_bounds__(256) void gemm_bt_f32(const unsigned short* __restrict__ A,
                                                   const unsigned short* __restrict__ BT,
                                                   const float* __restrict__ bias,
                                                   float* __restrict__ Cout,
                                                   int Mg, int Ng, int Kg) {
  __shared__ __align__(16) unsigned short lA[128 * 32];
  __shared__ __align__(16) unsigned short lB[128 * 32];
  const int tid = threadIdx.x;
  const int lane = tid & 63, wv = tid >> 6;
  const int g = lane >> 4, l16 = lane & 15;
  const int wr = wv >> 1, wc = wv & 1;
  const int rb = blockIdx.x * 128, cb = blockIdx.y * 128;

  f32x4 acc[4][4] = {};

  for (int k0 = 0; k0 < Kg; k0 += 32) {
    __syncthreads();
#pragma unroll
    for (int c = 0; c < 2; ++c) {
      int p = c * 256 + tid;
      int row = p >> 2;
      int k8l = (p & 3) ^ xsw(row);
      load16(A + (size_t)(rb + row) * Kg + k0 + 8 * k8l, (char*)lA + p * 16);
      load16(BT + (size_t)(cb + row) * Kg + k0 + 8 * k8l, (char*)lB + p * 16);
    }
    __syncthreads();
    bf16x8 af[4], bfr[4];
#pragma unroll
    for (int m = 0; m < 4; ++m) {
      int row = wr * 64 + m * 16 + l16;
      af[m] = *(const bf16x8*)((const char*)lA + (size_t)(row * 4 + (g ^ xsw(row))) * 16);
    }
#pragma unroll
    for (int n = 0; n < 4; ++n) {
      int row = wc * 64 + n * 16 + l16;
      bfr[n] = *(const bf16x8*)((const char*)lB + (size_t)(row * 4 + (g ^ xsw(row))) * 16);
    }
#pragma unroll
    for (int m = 0; m < 4; ++m)
#pragma unroll
      for (int n = 0; n < 4; ++n)
        acc[m][n] = mfma16(af[m], bfr[n], acc[m][n]);
  }

  const int ccol0 = cb + wc * 64 + l16;
  float bv[4];
#pragma unroll
  for (int n = 0; n < 4; ++n) bv[n] = bias[ccol0 + n * 16];
#pragma unroll
  for (int m = 0; m < 4; ++m)
#pragma unroll
    for (int r = 0; r < 4; ++r) {
      int row = rb + wr * 64 + m * 16 + g * 4 + r;
      float* p = Cout + (size_t)row * Ng + ccol0;
      p[0] = acc[m][0][r] + bv[0];
      p[16] = acc[m][1][r] + bv[1];
      p[32] = acc[m][2][r] + bv[2];
      p[48] = acc[m][3][r] + bv[3];
    }
}

// ----------------------------------------------------------- flash attention
DEV void stage_kv(const unsigned short* __restrict__ qkv,
                  const unsigned short* __restrict__ vt,
                  unsigned char* lds, int bS, int bh64, int hoff, int kvb, int buf, int tid) {
#pragma unroll
  for (int c = 0; c < 2; ++c) {
    int p = c * 256 + tid;
    int row = p >> 3, k8 = (p & 7) ^ (row & 7);
    load16(qkv + (size_t)(bS + kvb + row) * N3_ + 2048 + hoff + 8 * k8,
           lds + buf * 8192 + p * 16);
    load16(vt + (size_t)(bh64 + row) * S_ + kvb + 8 * k8,
           lds + 16384 + buf * 8192 + p * 16);
  }
}

__global__ __launch_bounds__(256, 3) void attn_kernel(const unsigned short* __restrict__ qkv,
                                                      const unsigned short* __restrict__ vt,
                                                      unsigned short* __restrict__ ao) {
  __shared__ __align__(16) unsigned char lds[49152];
  const int tid = threadIdx.x;
  const int lane = tid & 63, wv = tid >> 6;
  const int g = lane >> 4, l16 = lane & 15;
  const int bid = blockIdx.x;
  const int qi = 15 - (bid >> 6);
  const int t6 = bid & 63;
  const int bh = ((t6 & 7) << 3) | (t6 >> 3);
  const int b = bh >> 5, h = bh & 31;
  const int qbase = qi * 128;
  const int srow0 = qbase + wv * 32;
  const int bS = b * S_, bh64 = bh * 64, hoff = h * 64;

  bf16x8 qf[2][2];
#pragma unroll
  for (int m = 0; m < 2; ++m)
#pragma unroll
    for (int kt = 0; kt < 2; ++kt)
      qf[m][kt] = *(const bf16x8*)(qkv + (size_t)(bS + srow0 + m * 16 + l16) * N3_ +
                                   hoff + kt * 32 + g * 8);

  float mrun[2] = {-INFINITY, -INFINITY}, lrun[2] = {0.f, 0.f};
  f32x4 o[2][4] = {};
  unsigned char* pw = lds + 32768 + wv * 4096;

  const int nkv = (qbase + 128) >> 6;
  stage_kv(qkv, vt, lds, bS, bh64, hoff, 0, 0, tid);
  __syncthreads();

  for (int kb = 0; kb < nkv; ++kb) {
    const int cur = kb & 1;
    if (kb + 1 < nkv) stage_kv(qkv, vt, lds, bS, bh64, hoff, (kb + 1) << 6, cur ^ 1, tid);
    const int kvb = kb << 6;
    if (kvb <= srow0 + 31) {
      const unsigned char* kbuf = lds + cur * 8192;
      const unsigned char* vbuf = lds + 16384 + cur * 8192;

      f32x4 sc[2][4];
#pragma unroll
      for (int n = 0; n < 4; ++n) {
        int row = n * 16 + l16;
        bf16x8 kf0 = *(const bf16x8*)(kbuf + (row * 8 + ((g + 0) ^ (row & 7))) * 16);
        bf16x8 kf1 = *(const bf16x8*)(kbuf + (row * 8 + ((g + 4) ^ (row & 7))) * 16);
#pragma unroll
        for (int m = 0; m < 2; ++m) {
          f32x4 z = {};
          z = mfma16(kf0, qf[m][0], z);
          z = mfma16(kf1, qf[m][1], z);
          sc[m][n] = z;
        }
      }

      const bool boundary = (kvb + 63 > srow0);
#pragma unroll
      for (int m = 0; m < 2; ++m) {
        const int qrow = srow0 + m * 16 + l16;
        if (boundary) {
#pragma unroll
          for (int n = 0; n < 4; ++n)
#pragma unroll
            for (int r = 0; r < 4; ++r) {
              int k = kvb + n * 16 + g * 4 + r;
              if (k > qrow) sc[m][n][r] = -INFINITY;
            }
        }
        float mx = fmaxf(fmaxf(sc[m][0][0], sc[m][0][1]), fmaxf(sc[m][0][2], sc[m][0][3]));
#pragma unroll
        for (int n = 1; n < 4; ++n)
          mx = fmaxf(mx, fmaxf(fmaxf(sc[m][n][0], sc[m][n][1]), fmaxf(sc[m][n][2], sc[m][n][3])));
        mx = fmaxf(mx, __shfl_xor(mx, 16));
        mx = fmaxf(mx, __shfl_xor(mx, 32));
        float pm = mx * 0.125f;
        if (!__all(pm <= mrun[m] + 8.0f)) {
          float mn = fmaxf(mrun[m], pm);
          float al = exp2f((mrun[m] - mn) * 1.44269504f);
          mrun[m] = mn; lrun[m] *= al;
#pragma unroll
          for (int d = 0; d < 4; ++d) o[m][d] *= al;
        }
        const float mt = mrun[m] * 1.44269504f;
        float p[4][4]; float rs = 0.f;
#pragma unroll
        for (int n = 0; n < 4; ++n)
#pragma unroll
          for (int r = 0; r < 4; ++r) {
            p[n][r] = exp2f(fmaf(sc[m][n][r], 0.18033688011112042f, -mt));
            rs += p[n][r];
          }
        rs += __shfl_xor(rs, 16);
        rs += __shfl_xor(rs, 32);
        lrun[m] += rs;
#pragma unroll
        for (int n = 0; n < 4; ++n) {
          unsigned lo, hi;
          asm("v_cvt_pk_bf16_f32 %0, %1, %2" : "=v"(lo) : "v"(p[n][0]), "v"(p[n][1]));
          asm("v_cvt_pk_bf16_f32 %0, %1, %2" : "=v"(hi) : "v"(p[n][2]), "v"(p[n][3]));
          int su = (n * 4 + g) ^ ((l16 & 7) << 1);
          u32x2 wq; wq[0] = lo; wq[1] = hi;
          *(u32x2*)(pw + ((m * 16 + l16) * 16 + su) * 8) = wq;
        }
      }

      bf16x8 pf[2][2];
#pragma unroll
      for (int m = 0; m < 2; ++m)
#pragma unroll
        for (int kt = 0; kt < 2; ++kt) {
          int su = (kt * 8 + g * 2) ^ ((l16 & 7) << 1);
          pf[m][kt] = *(const bf16x8*)(pw + ((m * 16 + l16) * 16 + su) * 8);
        }
#pragma unroll
      for (int dblk = 0; dblk < 4; ++dblk) {
        int row = dblk * 16 + l16;
        bf16x8 vf0 = *(const bf16x8*)(vbuf + (row * 8 + ((g + 0) ^ (row & 7))) * 16);
        bf16x8 vf1 = *(const bf16x8*)(vbuf + (row * 8 + ((g + 4) ^ (row & 7))) * 16);
#pragma unroll
        for (int m = 0; m < 2; ++m) {
          o[m][dblk] = mfma16(vf0, pf[m][0], o[m][dblk]);
          o[m][dblk] = mfma16(vf1, pf[m][1], o[m][dblk]);
        }
      }
    }
    __syncthreads();
  }

#pragma unroll
  for (int m = 0; m < 2; ++m) {
    float inv = 1.0f / lrun[m];
    int q = srow0 + m * 16 + l16;
#pragma unroll
    for (int dblk = 0; dblk < 4; ++dblk) {
      u16x4 ov;
#pragma unroll
      for (int r = 0; r < 4; ++r) ov[r] = f2bf(o[m][dblk][r] * inv);
      *(u16x4*)(ao + (size_t)(bS + q) * D_ + hoff + dblk * 16 + g * 4) = ov;
    }
  }
}

// ---------------------------------------------------------------------- launch
extern "C" void kernel_launch(void* const* d_in, const int* in_sizes, int n_in,
                              void* d_out, int out_size, void* d_ws, size_t ws_size,
                              hipStream_t stream) {
  const float* x = (const float*)d_in[0];
  const float* Wqkv = (const float*)d_in[1];
  const float* bqkv = (const float*)d_in[2];
  const float* Wout = (const float*)d_in[3];
  const float* bout = (const float*)d_in[4];
  float* out = (float*)d_out;

  char* ws = (char*)d_ws;
  unsigned short* Xb = (unsigned short*)(ws + 0);                  // 16 MiB (reused as AO)
  unsigned short* Wqkvt = (unsigned short*)(ws + 16777216);        // 24 MiB
  unsigned short* Woutt = (unsigned short*)(ws + 41943040);        // 8 MiB
  unsigned short* QKVb = (unsigned short*)(ws + 50331648);         // 48 MiB
  unsigned short* Vt = (unsigned short*)(ws + 100663296);          // 16 MiB
  unsigned short* AO = Xb;  // Xb is dead after gemm1

  cvt_bf16<<<4096, 256, 0, stream>>>(x, Xb, M_ * D_);
  transpose_bf16<<<dim3(192, 64), 256, 0, stream>>>(Wqkv, Wqkvt, 2048, 6144);
  transpose_bf16<<<dim3(64, 64), 256, 0, stream>>>(Wout, Woutt, 2048, 2048);
  gemm_qkv<<<512, 512, 0, stream>>>(Xb, Wqkvt, bqkv, QKVb, Vt, M_, N3_, D_);
  attn_kernel<<<1024, 256, 0, stream>>>(QKVb, Vt, AO);
  gemm_bt_f32<<<dim3(32, 16), 256, 0, stream>>>(AO, Woutt, bout, out, M_, D_, D_);
}

// Round 10
// 254.906 us; speedup vs baseline: 1.1849x; 1.0400x over previous
//
#include <hip/hip_runtime.h>
#include <stdint.h>
#include <math.h>

#define DEV static __device__ __forceinline__

typedef __attribute__((ext_vector_type(8))) short bf16x8;
typedef __attribute__((ext_vector_type(4))) float f32x4;
typedef __attribute__((ext_vector_type(8))) unsigned short u16x8;
typedef __attribute__((ext_vector_type(4))) unsigned short u16x4;
typedef __attribute__((ext_vector_type(2))) unsigned int u32x2;

enum { B_ = 2, S_ = 2048, D_ = 2048, H_ = 32, HD_ = 64, N3_ = 6144, M_ = 4096 };

DEV unsigned short f2bf(float f) {
  unsigned u = __float_as_uint(f);
  u += 0x7FFFu + ((u >> 16) & 1u);
  return (unsigned short)(u >> 16);
}
DEV float bf2f(unsigned short s) { return __uint_as_float(((unsigned)s) << 16); }

DEV void load16(const void* g, void* l) {
  __builtin_amdgcn_global_load_lds((const __attribute__((address_space(1))) void*)g,
                                   (__attribute__((address_space(3))) void*)l,
                                   16, 0, 0);
}

DEV f32x4 mfma16(bf16x8 a, bf16x8 b, f32x4 c) {
  return __builtin_amdgcn_mfma_f32_16x16x32_bf16(a, b, c, 0, 0, 0);
}

// ---------------------------------------------------------------- cvt f32->bf16
__global__ __launch_bounds__(256) void cvt_bf16(const float* __restrict__ in,
                                                unsigned short* __restrict__ out, int n) {
  int i = blockIdx.x * 256 + threadIdx.x;
  if (i * 8 >= n) return;
  const float4* in4 = (const float4*)in;
  float4 a = in4[i * 2 + 0];
  float4 b = in4[i * 2 + 1];
  u16x8 o;
  o[0] = f2bf(a.x); o[1] = f2bf(a.y); o[2] = f2bf(a.z); o[3] = f2bf(a.w);
  o[4] = f2bf(b.x); o[5] = f2bf(b.y); o[6] = f2bf(b.z); o[7] = f2bf(b.w);
  *(u16x8*)(out + (size_t)i * 8) = o;
}

// ------------------------------------------- transpose f32 [K][N] -> bf16 [N][K]
__global__ __launch_bounds__(256) void transpose_bf16(const float* __restrict__ W,
                                                      unsigned short* __restrict__ Wt,
                                                      int Kg, int Ng) {
  __shared__ float tile[32][33];
  const int tn = blockIdx.x, tk = blockIdx.y;
  const int t = threadIdx.x;
  const int r = t >> 3, c4 = (t & 7) * 4;
  float4 v = *(const float4*)(W + (size_t)(tk * 32 + r) * Ng + tn * 32 + c4);
  tile[r][c4 + 0] = v.x; tile[r][c4 + 1] = v.y;
  tile[r][c4 + 2] = v.z; tile[r][c4 + 3] = v.w;
  __syncthreads();
  u16x4 o;
  o[0] = f2bf(tile[c4 + 0][r]);
  o[1] = f2bf(tile[c4 + 1][r]);
  o[2] = f2bf(tile[c4 + 2][r]);
  o[3] = f2bf(tile[c4 + 3][r]);
  *(u16x4*)(Wt + (size_t)(tn * 32 + r) * Kg + tk * 32 + c4) = o;
}

// ============ 128x192 QKV GEMM, BK=64, 2-phase pipelined, 2 blocks/CU =========
// A: [4096][2048] bf16, BT: [6144][2048] bf16. 256 thr = 4 waves; each wave =
// all 128 rows x 3 scattered 16-col groups (RoPE pairs intra-wave).
// LDS 80KB: buf at {0,40960}: A 16KB (4 chunks of 32 rows) | B 24KB (6 chunks).
// Exactly 2 blocks/CU (163840 B LDS) -> barrier-independent co-residency fills
// the other block's drain gaps (m114 mechanism).
// Row=128B=8 units of 16B; unit u holds k8 = u^(row&7); linear gload dest with
// inverse-swizzled global source.
// vmcnt ledger (SA0=2,SA1=2,SB=6): prologue 8; P2-entry 10; exit 10; tail 2/0.
__global__ __launch_bounds__(256, 2) void gemm_qkv(const unsigned short* __restrict__ A,
                                                   const unsigned short* __restrict__ BT,
                                                   const float* __restrict__ bias,
                                                   unsigned short* __restrict__ Oqk,
                                                   unsigned short* __restrict__ vt,
                                                   int Mg, int Ng, int Kg) {
  __shared__ __align__(16) char lds[81920];
  const int tid = threadIdx.x;
  const int lane = tid & 63, w = tid >> 6;
  const int g = (lane >> 4) & 3, l16 = lane & 15;
  const int wn = w;

  // XCD-bijective swizzle (1024 % 8 == 0), tm fastest (B-panel L2 reuse).
  const int wg = (blockIdx.x & 7) * (gridDim.x >> 3) + (blockIdx.x >> 3);
  const int nTM = Mg >> 7;
  const int tm = wg % nTM, tn = wg / nTM;
  const int rb = tm * 128, cb = tn * 192;
  const int NT = Kg >> 6;

  // column-group table (rotary pair = groups 0,1 when wn<3)
  int c0, c1, c2;
  if (wn == 0)      { c0 = 0;   c1 = 16;  c2 = 32;  }
  else if (wn == 1) { c0 = 64;  c1 = 80;  c2 = 48;  }
  else if (wn == 2) { c0 = 128; c1 = 144; c2 = 96;  }
  else              { c0 = 112; c1 = 160; c2 = 176; }

  const int su0 = (g ^ (l16 & 7)) * 16;
  const int su1 = ((4 + g) ^ (l16 & 7)) * 16;
  const int offA = l16 * 128;
  const int offB0 = 16384 + (c0 + l16) * 128;
  const int offB1 = 16384 + (c1 + l16) * 128;
  const int offB2 = 16384 + (c2 + l16) * 128;

  // staging (chunk = 32 rows; dest linear, source inverse-swizzled)
  const int r0 = tid >> 3;
  const int u8e = ((tid & 7) ^ (r0 & 7)) * 8;
  const unsigned short* sAa = A + (size_t)(rb + r0) * Kg + u8e;
  const unsigned short* sBb = BT + (size_t)(cb + r0) * Kg + u8e;
  const size_t rs32 = (size_t)Kg * 32;
  const int dstb = tid * 16;

  auto SA0 = [&](int t) { char* db = (char*)lds + ((t & 1) ? 40960 : 0);
    load16(sAa + (size_t)t * 64, db + dstb);
    load16(sAa + rs32 + (size_t)t * 64, db + 4096 + dstb); };
  auto SA1 = [&](int t) { char* db = (char*)lds + ((t & 1) ? 40960 : 0);
    load16(sAa + 2 * rs32 + (size_t)t * 64, db + 8192 + dstb);
    load16(sAa + 3 * rs32 + (size_t)t * 64, db + 12288 + dstb); };
  auto SB = [&](int t) { char* db = (char*)lds + ((t & 1) ? 40960 : 0) + 16384;
#pragma unroll
    for (int c = 0; c < 6; ++c)
      load16(sBb + c * rs32 + (size_t)t * 64, db + c * 4096 + dstb); };

  // prologue: tile0 full (10) + tile1 {A0,B} (8); vmcnt(8) drains tile0
  SA0(0); SA1(0); SB(0); SA0(1); SB(1);
  asm volatile("s_waitcnt vmcnt(8)" ::: "memory");
  __builtin_amdgcn_s_barrier();

  f32x4 acc[8][3] = {};
  bf16x8 a[4][2], b[3][2];

  for (int t = 0; t < NT; ++t) {
    const char* bs = (const char*)lds + ((t & 1) ? 40960 : 0);
    // ---- P1: read A rows 0-63 + all 3 B groups; stage A1(t+1)
#pragma unroll
    for (int mf = 0; mf < 4; ++mf) {
      a[mf][0] = *(const bf16x8*)(bs + offA + mf * 2048 + su0);
      a[mf][1] = *(const bf16x8*)(bs + offA + mf * 2048 + su1);
    }
    b[0][0] = *(const bf16x8*)(bs + offB0 + su0);
    b[0][1] = *(const bf16x8*)(bs + offB0 + su1);
    b[1][0] = *(const bf16x8*)(bs + offB1 + su0);
    b[1][1] = *(const bf16x8*)(bs + offB1 + su1);
    b[2][0] = *(const bf16x8*)(bs + offB2 + su0);
    b[2][1] = *(const bf16x8*)(bs + offB2 + su1);
    if (t + 1 < NT) SA1(t + 1);
    asm volatile("s_waitcnt lgkmcnt(8)" ::: "memory");
    __builtin_amdgcn_s_barrier();
    asm volatile("s_waitcnt lgkmcnt(0)" ::: "memory");
    __builtin_amdgcn_s_setprio(1);
#pragma unroll
    for (int mf = 0; mf < 4; ++mf)
#pragma unroll
      for (int nf = 0; nf < 3; ++nf)
#pragma unroll
        for (int kh = 0; kh < 2; ++kh)
          acc[mf][nf] = mfma16(a[mf][kh], b[nf][kh], acc[mf][nf]);
    __builtin_amdgcn_s_setprio(0);
    __builtin_amdgcn_s_barrier();
    // ---- P2: entry vmcnt gates A1(t); read A rows 64-127; stage A0/B(t+2)
    if (t == NT - 1) asm volatile("s_waitcnt vmcnt(0)" ::: "memory");
    else             asm volatile("s_waitcnt vmcnt(10)" ::: "memory");
#pragma unroll
    for (int mf = 0; mf < 4; ++mf) {
      a[mf][0] = *(const bf16x8*)(bs + offA + (mf + 4) * 2048 + su0);
      a[mf][1] = *(const bf16x8*)(bs + offA + (mf + 4) * 2048 + su1);
    }
    if (t + 2 < NT) { SA0(t + 2); SB(t + 2); }
    __builtin_amdgcn_s_barrier();
    asm volatile("s_waitcnt lgkmcnt(0)" ::: "memory");
    __builtin_amdgcn_s_setprio(1);
#pragma unroll
    for (int mf = 0; mf < 4; ++mf)
#pragma unroll
      for (int nf = 0; nf < 3; ++nf)
#pragma unroll
        for (int kh = 0; kh < 2; ++kh)
          acc[mf + 4][nf] = mfma16(a[mf][kh], b[nf][kh], acc[mf + 4][nf]);
    __builtin_amdgcn_s_setprio(0);
    if (t + 2 < NT)      asm volatile("s_waitcnt vmcnt(10)" ::: "memory");
    else if (t + 1 < NT) asm volatile("s_waitcnt vmcnt(2)" ::: "memory");
    __builtin_amdgcn_s_barrier();
  }

  // ---- epilogue: fused RoPE (groups 0,1 when rotary) + V transposed store
  const int crow0 = rb + g * 4;
  const float bv0 = bias[cb + c0 + l16];
  const float bv1 = bias[cb + c1 + l16];
  const float bv2 = bias[cb + c2 + l16];
  const bool rotp = (wn < 3) && (cb + c0 < 4096);
  const float invf = exp2f(-(float)l16 * 0.83048202372184056f);  // 10000^(-l16/16)

#define STOREG(NF, CG, BV) do {                                                \
    const int col0_ = cb + (CG);                                               \
    if (col0_ >= 4096) {                                                       \
      const int hv_ = (col0_ - 4096) >> 6;                                     \
      const int dd_ = (col0_ & 63) + l16;                                      \
      _Pragma("unroll")                                                        \
      for (int mf = 0; mf < 8; ++mf) {                                         \
        int rowb_ = crow0 + mf * 16;                                           \
        int bb_ = rowb_ >> 11, s0_ = rowb_ & (S_ - 1);                         \
        u16x4 ov_;                                                             \
        _Pragma("unroll")                                                      \
        for (int r = 0; r < 4; ++r) ov_[r] = f2bf(acc[mf][NF][r] + (BV));      \
        *(u16x4*)(vt + ((size_t)(bb_ * 32 + hv_) * 64 + dd_) * S_ + s0_) = ov_;\
      }                                                                        \
    } else {                                                                   \
      _Pragma("unroll")                                                        \
      for (int mf = 0; mf < 8; ++mf)                                           \
        _Pragma("unroll")                                                      \
        for (int r = 0; r < 4; ++r) {                                          \
          int row_ = crow0 + mf * 16 + r;                                      \
          Oqk[(size_t)row_ * Ng + col0_ + l16] = f2bf(acc[mf][NF][r] + (BV));  \
        }                                                                      \
    }                                                                          \
  } while (0)

  if (rotp) {
#pragma unroll
    for (int mf = 0; mf < 8; ++mf)
#pragma unroll
      for (int r = 0; r < 4; ++r) {
        int row = crow0 + mf * 16 + r;
        float v0 = acc[mf][0][r] + bv0;
        float v1 = acc[mf][1][r] + bv1;
        float ang = (float)(row & (S_ - 1)) * invf;
        float sn = __sinf(ang), cs = __cosf(ang);
        float t0 = v0 * cs - v1 * sn;
        v1 = v0 * sn + v1 * cs;
        unsigned short* p = Oqk + (size_t)row * Ng;
        p[cb + c0 + l16] = f2bf(t0);
        p[cb + c1 + l16] = f2bf(v1);
      }
  } else {
    STOREG(0, c0, bv0);
    STOREG(1, c1, bv1);
  }
  STOREG(2, c2, bv2);
#undef STOREG
}

// ------------------------------------------------------------- GEMM C = A @ B^T
// 128x128 tile, BK=32, 32KB LDS, ~3 blocks/CU (m97 structure) — GEMM3.
DEV int xsw(int row) { return (row ^ (row >> 2)) & 3; }

__global__ __launch_bounds__(256) void gemm_bt_f32(const unsigned short* __restrict__ A,
                                                   const unsigned short* __restrict__ BT,
                                                   const float* __restrict__ bias,
                                                   float* __restrict__ Cout,
                                                   int Mg, int Ng, int Kg) {
  __shared__ __align__(16) unsigned short lA[128 * 32];
  __shared__ __align__(16) unsigned short lB[128 * 32];
  const int tid = threadIdx.x;
  const int lane = tid & 63, wv = tid >> 6;
  const int g = lane >> 4, l16 = lane & 15;
  const int wr = wv >> 1, wc = wv & 1;
  const int rb = blockIdx.x * 128, cb = blockIdx.y * 128;

  f32x4 acc[4][4] = {};

  for (int k0 = 0; k0 < Kg; k0 += 32) {
    __syncthreads();
#pragma unroll
    for (int c = 0; c < 2; ++c) {
      int p = c * 256 + tid;
      int row = p >> 2;
      int k8l = (p & 3) ^ xsw(row);
      load16(A + (size_t)(rb + row) * Kg + k0 + 8 * k8l, (char*)lA + p * 16);
      load16(BT + (size_t)(cb + row) * Kg + k0 + 8 * k8l, (char*)lB + p * 16);
    }
    __syncthreads();
    bf16x8 af[4], bfr[4];
#pragma unroll
    for (int m = 0; m < 4; ++m) {
      int row = wr * 64 + m * 16 + l16;
      af[m] = *(const bf16x8*)((const char*)lA + (size_t)(row * 4 + (g ^ xsw(row))) * 16);
    }
#pragma unroll
    for (int n = 0; n < 4; ++n) {
      int row = wc * 64 + n * 16 + l16;
      bfr[n] = *(const bf16x8*)((const char*)lB + (size_t)(row * 4 + (g ^ xsw(row))) * 16);
    }
#pragma unroll
    for (int m = 0; m < 4; ++m)
#pragma unroll
      for (int n = 0; n < 4; ++n)
        acc[m][n] = mfma16(af[m], bfr[n], acc[m][n]);
  }

  const int ccol0 = cb + wc * 64 + l16;
  float bv[4];
#pragma unroll
  for (int n = 0; n < 4; ++n) bv[n] = bias[ccol0 + n * 16];
#pragma unroll
  for (int m = 0; m < 4; ++m)
#pragma unroll
    for (int r = 0; r < 4; ++r) {
      int row = rb + wr * 64 + m * 16 + g * 4 + r;
      float* p = Cout + (size_t)row * Ng + ccol0;
      p[0] = acc[m][0][r] + bv[0];
      p[16] = acc[m][1][r] + bv[1];
      p[32] = acc[m][2][r] + bv[2];
      p[48] = acc[m][3][r] + bv[3];
    }
}

// ----------------------------------------------------------- flash attention
DEV void stage_kv(const unsigned short* __restrict__ qkv,
                  const unsigned short* __restrict__ vt,
                  unsigned char* lds, int bS, int bh64, int hoff, int kvb, int buf, int tid) {
#pragma unroll
  for (int c = 0; c < 2; ++c) {
    int p = c * 256 + tid;
    int row = p >> 3, k8 = (p & 7) ^ (row & 7);
    load16(qkv + (size_t)(bS + kvb + row) * N3_ + 2048 + hoff + 8 * k8,
           lds + buf * 8192 + p * 16);
    load16(vt + (size_t)(bh64 + row) * S_ + kvb + 8 * k8,
           lds + 16384 + buf * 8192 + p * 16);
  }
}

__global__ __launch_bounds__(256, 3) void attn_kernel(const unsigned short* __restrict__ qkv,
                                                      const unsigned short* __restrict__ vt,
                                                      unsigned short* __restrict__ ao) {
  __shared__ __align__(16) unsigned char lds[49152];
  const int tid = threadIdx.x;
  const int lane = tid & 63, wv = tid >> 6;
  const int g = lane >> 4, l16 = lane & 15;
  const int bid = blockIdx.x;
  const int qi = 15 - (bid >> 6);
  const int t6 = bid & 63;
  const int bh = ((t6 & 7) << 3) | (t6 >> 3);
  const int b = bh >> 5, h = bh & 31;
  const int qbase = qi * 128;
  const int srow0 = qbase + wv * 32;
  const int bS = b * S_, bh64 = bh * 64, hoff = h * 64;

  bf16x8 qf[2][2];
#pragma unroll
  for (int m = 0; m < 2; ++m)
#pragma unroll
    for (int kt = 0; kt < 2; ++kt)
      qf[m][kt] = *(const bf16x8*)(qkv + (size_t)(bS + srow0 + m * 16 + l16) * N3_ +
                                   hoff + kt * 32 + g * 8);

  float mrun[2] = {-INFINITY, -INFINITY}, lrun[2] = {0.f, 0.f};
  f32x4 o[2][4] = {};
  unsigned char* pw = lds + 32768 + wv * 4096;

  const int nkv = (qbase + 128) >> 6;
  stage_kv(qkv, vt, lds, bS, bh64, hoff, 0, 0, tid);
  __syncthreads();

  for (int kb = 0; kb < nkv; ++kb) {
    const int cur = kb & 1;
    if (kb + 1 < nkv) stage_kv(qkv, vt, lds, bS, bh64, hoff, (kb + 1) << 6, cur ^ 1, tid);
    const int kvb = kb << 6;
    if (kvb <= srow0 + 31) {
      const unsigned char* kbuf = lds + cur * 8192;
      const unsigned char* vbuf = lds + 16384 + cur * 8192;

      f32x4 sc[2][4];
#pragma unroll
      for (int n = 0; n < 4; ++n) {
        int row = n * 16 + l16;
        bf16x8 kf0 = *(const bf16x8*)(kbuf + (row * 8 + ((g + 0) ^ (row & 7))) * 16);
        bf16x8 kf1 = *(const bf16x8*)(kbuf + (row * 8 + ((g + 4) ^ (row & 7))) * 16);
#pragma unroll
        for (int m = 0; m < 2; ++m) {
          f32x4 z = {};
          z = mfma16(kf0, qf[m][0], z);
          z = mfma16(kf1, qf[m][1], z);
          sc[m][n] = z;
        }
      }

      const bool boundary = (kvb + 63 > srow0);
#pragma unroll
      for (int m = 0; m < 2; ++m) {
        const int qrow = srow0 + m * 16 + l16;
        if (boundary) {
#pragma unroll
          for (int n = 0; n < 4; ++n)
#pragma unroll
            for (int r = 0; r < 4; ++r) {
              int k = kvb + n * 16 + g * 4 + r;
              if (k > qrow) sc[m][n][r] = -INFINITY;
            }
        }
        float mx = fmaxf(fmaxf(sc[m][0][0], sc[m][0][1]), fmaxf(sc[m][0][2], sc[m][0][3]));
#pragma unroll
        for (int n = 1; n < 4; ++n)
          mx = fmaxf(mx, fmaxf(fmaxf(sc[m][n][0], sc[m][n][1]), fmaxf(sc[m][n][2], sc[m][n][3])));
        mx = fmaxf(mx, __shfl_xor(mx, 16));
        mx = fmaxf(mx, __shfl_xor(mx, 32));
        float pm = mx * 0.125f;
        if (!__all(pm <= mrun[m] + 8.0f)) {
          float mn = fmaxf(mrun[m], pm);
          float al = exp2f((mrun[m] - mn) * 1.44269504f);
          mrun[m] = mn; lrun[m] *= al;
#pragma unroll
          for (int d = 0; d < 4; ++d) o[m][d] *= al;
        }
        const float mt = mrun[m] * 1.44269504f;
        float p[4][4]; float rs = 0.f;
#pragma unroll
        for (int n = 0; n < 4; ++n)
#pragma unroll
          for (int r = 0; r < 4; ++r) {
            p[n][r] = exp2f(fmaf(sc[m][n][r], 0.18033688011112042f, -mt));
            rs += p[n][r];
          }
        rs += __shfl_xor(rs, 16);
        rs += __shfl_xor(rs, 32);
        lrun[m] += rs;
#pragma unroll
        for (int n = 0; n < 4; ++n) {
          unsigned lo, hi;
          asm("v_cvt_pk_bf16_f32 %0, %1, %2" : "=v"(lo) : "v"(p[n][0]), "v"(p[n][1]));
          asm("v_cvt_pk_bf16_f32 %0, %1, %2" : "=v"(hi) : "v"(p[n][2]), "v"(p[n][3]));
          int su = (n * 4 + g) ^ ((l16 & 7) << 1);
          u32x2 wq; wq[0] = lo; wq[1] = hi;
          *(u32x2*)(pw + ((m * 16 + l16) * 16 + su) * 8) = wq;
        }
      }

      bf16x8 pf[2][2];
#pragma unroll
      for (int m = 0; m < 2; ++m)
#pragma unroll
        for (int kt = 0; kt < 2; ++kt) {
          int su = (kt * 8 + g * 2) ^ ((l16 & 7) << 1);
          pf[m][kt] = *(const bf16x8*)(pw + ((m * 16 + l16) * 16 + su) * 8);
        }
#pragma unroll
      for (int dblk = 0; dblk < 4; ++dblk) {
        int row = dblk * 16 + l16;
        bf16x8 vf0 = *(const bf16x8*)(vbuf + (row * 8 + ((g + 0) ^ (row & 7))) * 16);
        bf16x8 vf1 = *(const bf16x8*)(vbuf + (row * 8 + ((g + 4) ^ (row & 7))) * 16);
#pragma unroll
        for (int m = 0; m < 2; ++m) {
          o[m][dblk] = mfma16(vf0, pf[m][0], o[m][dblk]);
          o[m][dblk] = mfma16(vf1, pf[m][1], o[m][dblk]);
        }
      }
    }
    __syncthreads();
  }

#pragma unroll
  for (int m = 0; m < 2; ++m) {
    float inv = 1.0f / lrun[m];
    int q = srow0 + m * 16 + l16;
#pragma unroll
    for (int dblk = 0; dblk < 4; ++dblk) {
      u16x4 ov;
#pragma unroll
      for (int r = 0; r < 4; ++r) ov[r] = f2bf(o[m][dblk][r] * inv);
      *(u16x4*)(ao + (size_t)(bS + q) * D_ + hoff + dblk * 16 + g * 4) = ov;
    }
  }
}

// ---------------------------------------------------------------------- launch
extern "C" void kernel_launch(void* const* d_in, const int* in_sizes, int n_in,
                              void* d_out, int out_size, void* d_ws, size_t ws_size,
                              hipStream_t stream) {
  const float* x = (const float*)d_in[0];
  const float* Wqkv = (const float*)d_in[1];
  const float* bqkv = (const float*)d_in[2];
  const float* Wout = (const float*)d_in[3];
  const float* bout = (const float*)d_in[4];
  float* out = (float*)d_out;

  char* ws = (char*)d_ws;
  unsigned short* Xb = (unsigned short*)(ws + 0);                  // 16 MiB (reused as AO)
  unsigned short* Wqkvt = (unsigned short*)(ws + 16777216);        // 24 MiB
  unsigned short* Woutt = (unsigned short*)(ws + 41943040);        // 8 MiB
  unsigned short* QKVb = (unsigned short*)(ws + 50331648);         // 48 MiB
  unsigned short* Vt = (unsigned short*)(ws + 100663296);          // 16 MiB
  unsigned short* AO = Xb;  // Xb is dead after gemm1

  cvt_bf16<<<4096, 256, 0, stream>>>(x, Xb, M_ * D_);
  transpose_bf16<<<dim3(192, 64), 256, 0, stream>>>(Wqkv, Wqkvt, 2048, 6144);
  transpose_bf16<<<dim3(64, 64), 256, 0, stream>>>(Wout, Woutt, 2048, 2048);
  gemm_qkv<<<1024, 256, 0, stream>>>(Xb, Wqkvt, bqkv, QKVb, Vt, M_, N3_, D_);
  attn_kernel<<<1024, 256, 0, stream>>>(QKVb, Vt, AO);
  gemm_bt_f32<<<dim3(32, 16), 256, 0, stream>>>(AO, Woutt, bout, out, M_, D_, D_);
}

// Round 12
// 236.330 us; speedup vs baseline: 1.2780x; 1.0786x over previous
//
#include <hip/hip_runtime.h>
#include <stdint.h>
#include <math.h>

#define DEV static __device__ __forceinline__

typedef __attribute__((ext_vector_type(8))) short bf16x8;
typedef __attribute__((ext_vector_type(4))) float f32x4;
typedef __attribute__((ext_vector_type(8))) unsigned short u16x8;
typedef __attribute__((ext_vector_type(4))) unsigned short u16x4;
typedef __attribute__((ext_vector_type(2))) unsigned int u32x2;

enum { B_ = 2, S_ = 2048, D_ = 2048, H_ = 32, HD_ = 64, N3_ = 6144, M_ = 4096 };

DEV unsigned short f2bf(float f) {
  unsigned u = __float_as_uint(f);
  u += 0x7FFFu + ((u >> 16) & 1u);
  return (unsigned short)(u >> 16);
}
DEV float bf2f(unsigned short s) { return __uint_as_float(((unsigned)s) << 16); }

DEV void load16(const void* g, void* l) {
  __builtin_amdgcn_global_load_lds((const __attribute__((address_space(1))) void*)g,
                                   (__attribute__((address_space(3))) void*)l,
                                   16, 0, 0);
}

DEV f32x4 mfma16(bf16x8 a, bf16x8 b, f32x4 c) {
  return __builtin_amdgcn_mfma_f32_16x16x32_bf16(a, b, c, 0, 0, 0);
}

// ---------------------------------------------------------------- cvt f32->bf16
__global__ __launch_bounds__(256) void cvt_bf16(const float* __restrict__ in,
                                                unsigned short* __restrict__ out, int n) {
  int i = blockIdx.x * 256 + threadIdx.x;
  if (i * 8 >= n) return;
  const float4* in4 = (const float4*)in;
  float4 a = in4[i * 2 + 0];
  float4 b = in4[i * 2 + 1];
  u16x8 o;
  o[0] = f2bf(a.x); o[1] = f2bf(a.y); o[2] = f2bf(a.z); o[3] = f2bf(a.w);
  o[4] = f2bf(b.x); o[5] = f2bf(b.y); o[6] = f2bf(b.z); o[7] = f2bf(b.w);
  *(u16x8*)(out + (size_t)i * 8) = o;
}

// ------------------------------------------- transpose f32 [K][N] -> bf16 [N][K]
__global__ __launch_bounds__(256) void transpose_bf16(const float* __restrict__ W,
                                                      unsigned short* __restrict__ Wt,
                                                      int Kg, int Ng) {
  __shared__ float tile[32][33];
  const int tn = blockIdx.x, tk = blockIdx.y;
  const int t = threadIdx.x;
  const int r = t >> 3, c4 = (t & 7) * 4;
  float4 v = *(const float4*)(W + (size_t)(tk * 32 + r) * Ng + tn * 32 + c4);
  tile[r][c4 + 0] = v.x; tile[r][c4 + 1] = v.y;
  tile[r][c4 + 2] = v.z; tile[r][c4 + 3] = v.w;
  __syncthreads();
  u16x4 o;
  o[0] = f2bf(tile[c4 + 0][r]);
  o[1] = f2bf(tile[c4 + 1][r]);
  o[2] = f2bf(tile[c4 + 2][r]);
  o[3] = f2bf(tile[c4 + 3][r]);
  *(u16x4*)(Wt + (size_t)(tn * 32 + r) * Kg + tk * 32 + c4) = o;
}

// ============ 128x192 QKV GEMM, BK=64, 2-phase pipelined, 2 blocks/CU =========
// RACE FIX (r11): the vmcnt gating A1(t) reads must sit BEFORE the barrier
// (vmcnt drains only this wave's staged loads; barrier-after-vmcnt proves ALL
// waves' loads landed before any wave reads). Pattern: vmcnt -> barrier -> read.
__global__ __launch_bounds__(256, 2) void gemm_qkv(const unsigned short* __restrict__ A,
                                                   const unsigned short* __restrict__ BT,
                                                   const float* __restrict__ bias,
                                                   unsigned short* __restrict__ Oqk,
                                                   unsigned short* __restrict__ vt,
                                                   int Mg, int Ng, int Kg) {
  __shared__ __align__(16) char lds[81920];
  const int tid = threadIdx.x;
  const int lane = tid & 63, w = tid >> 6;
  const int g = (lane >> 4) & 3, l16 = lane & 15;
  const int wn = w;

  const int wg = (blockIdx.x & 7) * (gridDim.x >> 3) + (blockIdx.x >> 3);
  const int nTM = Mg >> 7;
  const int tm = wg % nTM, tn = wg / nTM;
  const int rb = tm * 128, cb = tn * 192;
  const int NT = Kg >> 6;

  int c0, c1, c2;
  if (wn == 0)      { c0 = 0;   c1 = 16;  c2 = 32;  }
  else if (wn == 1) { c0 = 64;  c1 = 80;  c2 = 48;  }
  else if (wn == 2) { c0 = 128; c1 = 144; c2 = 96;  }
  else              { c0 = 112; c1 = 160; c2 = 176; }

  const int su0 = (g ^ (l16 & 7)) * 16;
  const int su1 = ((4 + g) ^ (l16 & 7)) * 16;
  const int offA = l16 * 128;
  const int offB0 = 16384 + (c0 + l16) * 128;
  const int offB1 = 16384 + (c1 + l16) * 128;
  const int offB2 = 16384 + (c2 + l16) * 128;

  const int r0 = tid >> 3;
  const int u8e = ((tid & 7) ^ (r0 & 7)) * 8;
  const unsigned short* sAa = A + (size_t)(rb + r0) * Kg + u8e;
  const unsigned short* sBb = BT + (size_t)(cb + r0) * Kg + u8e;
  const size_t rs32 = (size_t)Kg * 32;
  const int dstb = tid * 16;

  auto SA0 = [&](int t) { char* db = (char*)lds + ((t & 1) ? 40960 : 0);
    load16(sAa + (size_t)t * 64, db + dstb);
    load16(sAa + rs32 + (size_t)t * 64, db + 4096 + dstb); };
  auto SA1 = [&](int t) { char* db = (char*)lds + ((t & 1) ? 40960 : 0);
    load16(sAa + 2 * rs32 + (size_t)t * 64, db + 8192 + dstb);
    load16(sAa + 3 * rs32 + (size_t)t * 64, db + 12288 + dstb); };
  auto SB = [&](int t) { char* db = (char*)lds + ((t & 1) ? 40960 : 0) + 16384;
#pragma unroll
    for (int c = 0; c < 6; ++c)
      load16(sBb + c * rs32 + (size_t)t * 64, db + c * 4096 + dstb); };

  SA0(0); SA1(0); SB(0); SA0(1); SB(1);
  asm volatile("s_waitcnt vmcnt(8)" ::: "memory");
  __builtin_amdgcn_s_barrier();

  f32x4 acc[8][3] = {};
  bf16x8 a[4][2], b[3][2];

  for (int t = 0; t < NT; ++t) {
    const char* bs = (const char*)lds + ((t & 1) ? 40960 : 0);
    // ---- P1: read A rows 0-63 + all 3 B groups; stage A1(t+1)
#pragma unroll
    for (int mf = 0; mf < 4; ++mf) {
      a[mf][0] = *(const bf16x8*)(bs + offA + mf * 2048 + su0);
      a[mf][1] = *(const bf16x8*)(bs + offA + mf * 2048 + su1);
    }
    b[0][0] = *(const bf16x8*)(bs + offB0 + su0);
    b[0][1] = *(const bf16x8*)(bs + offB0 + su1);
    b[1][0] = *(const bf16x8*)(bs + offB1 + su0);
    b[1][1] = *(const bf16x8*)(bs + offB1 + su1);
    b[2][0] = *(const bf16x8*)(bs + offB2 + su0);
    b[2][1] = *(const bf16x8*)(bs + offB2 + su1);
    if (t + 1 < NT) SA1(t + 1);
    asm volatile("s_waitcnt lgkmcnt(8)" ::: "memory");
    __builtin_amdgcn_s_barrier();
    asm volatile("s_waitcnt lgkmcnt(0)" ::: "memory");
    __builtin_amdgcn_s_setprio(1);
#pragma unroll
    for (int mf = 0; mf < 4; ++mf)
#pragma unroll
      for (int nf = 0; nf < 3; ++nf)
#pragma unroll
        for (int kh = 0; kh < 2; ++kh)
          acc[mf][nf] = mfma16(a[mf][kh], b[nf][kh], acc[mf][nf]);
    __builtin_amdgcn_s_setprio(0);
    // RACE FIX: drain this wave's SA1(t) BEFORE the barrier so the barrier
    // proves all waves' A1(t) landed; reads follow the barrier.
    if (t == NT - 1) asm volatile("s_waitcnt vmcnt(0)" ::: "memory");
    else             asm volatile("s_waitcnt vmcnt(10)" ::: "memory");
    __builtin_amdgcn_s_barrier();
    // ---- P2: read A rows 64-127; stage A0/B(t+2)
#pragma unroll
    for (int mf = 0; mf < 4; ++mf) {
      a[mf][0] = *(const bf16x8*)(bs + offA + (mf + 4) * 2048 + su0);
      a[mf][1] = *(const bf16x8*)(bs + offA + (mf + 4) * 2048 + su1);
    }
    if (t + 2 < NT) { SA0(t + 2); SB(t + 2); }
    __builtin_amdgcn_s_barrier();
    asm volatile("s_waitcnt lgkmcnt(0)" ::: "memory");
    __builtin_amdgcn_s_setprio(1);
#pragma unroll
    for (int mf = 0; mf < 4; ++mf)
#pragma unroll
      for (int nf = 0; nf < 3; ++nf)
#pragma unroll
        for (int kh = 0; kh < 2; ++kh)
          acc[mf + 4][nf] = mfma16(a[mf][kh], b[nf][kh], acc[mf + 4][nf]);
    __builtin_amdgcn_s_setprio(0);
    if (t + 2 < NT)      asm volatile("s_waitcnt vmcnt(10)" ::: "memory");
    else if (t + 1 < NT) asm volatile("s_waitcnt vmcnt(2)" ::: "memory");
    __builtin_amdgcn_s_barrier();
  }

  const int crow0 = rb + g * 4;
  const float bv0 = bias[cb + c0 + l16];
  const float bv1 = bias[cb + c1 + l16];
  const float bv2 = bias[cb + c2 + l16];
  const bool rotp = (wn < 3) && (cb + c0 < 4096);
  const float invf = exp2f(-(float)l16 * 0.83048202372184056f);  // 10000^(-l16/16)

#define STOREG(NF, CG, BV) do {                                                \
    const int col0_ = cb + (CG);                                               \
    if (col0_ >= 4096) {                                                       \
      const int hv_ = (col0_ - 4096) >> 6;                                     \
      const int dd_ = (col0_ & 63) + l16;                                      \
      _Pragma("unroll")                                                        \
      for (int mf = 0; mf < 8; ++mf) {                                         \
        int rowb_ = crow0 + mf * 16;                                           \
        int bb_ = rowb_ >> 11, s0_ = rowb_ & (S_ - 1);                         \
        u16x4 ov_;                                                             \
        _Pragma("unroll")                                                      \
        for (int r = 0; r < 4; ++r) ov_[r] = f2bf(acc[mf][NF][r] + (BV));      \
        *(u16x4*)(vt + ((size_t)(bb_ * 32 + hv_) * 64 + dd_) * S_ + s0_) = ov_;\
      }                                                                        \
    } else {                                                                   \
      _Pragma("unroll")                                                        \
      for (int mf = 0; mf < 8; ++mf)                                           \
        _Pragma("unroll")                                                      \
        for (int r = 0; r < 4; ++r) {                                          \
          int row_ = crow0 + mf * 16 + r;                                      \
          Oqk[(size_t)row_ * Ng + col0_ + l16] = f2bf(acc[mf][NF][r] + (BV));  \
        }                                                                      \
    }                                                                          \
  } while (0)

  if (rotp) {
#pragma unroll
    for (int mf = 0; mf < 8; ++mf)
#pragma unroll
      for (int r = 0; r < 4; ++r) {
        int row = crow0 + mf * 16 + r;
        float v0 = acc[mf][0][r] + bv0;
        float v1 = acc[mf][1][r] + bv1;
        float ang = (float)(row & (S_ - 1)) * invf;
        float sn = __sinf(ang), cs = __cosf(ang);
        float t0 = v0 * cs - v1 * sn;
        v1 = v0 * sn + v1 * cs;
        unsigned short* p = Oqk + (size_t)row * Ng;
        p[cb + c0 + l16] = f2bf(t0);
        p[cb + c1 + l16] = f2bf(v1);
      }
  } else {
    STOREG(0, c0, bv0);
    STOREG(1, c1, bv1);
  }
  STOREG(2, c2, bv2);
#undef STOREG
}

// ============ 128x128 OUT GEMM, BK=64, 2-phase pipelined, 2 blocks/CU =========
// Same RACE FIX as gemm_qkv: A1-gating vmcnt moved before the barrier.
__global__ __launch_bounds__(256, 2) void gemm_out(const unsigned short* __restrict__ A,
                                                   const unsigned short* __restrict__ BT,
                                                   const float* __restrict__ bias,
                                                   float* __restrict__ Cout,
                                                   int Mg, int Ng, int Kg) {
  __shared__ __align__(16) char lds[65536];
  const int tid = threadIdx.x;
  const int lane = tid & 63, w = tid >> 6;
  const int g = (lane >> 4) & 3, l16 = lane & 15;
  const int wn = w;

  const int wg = (blockIdx.x & 7) * (gridDim.x >> 3) + (blockIdx.x >> 3);
  const int nTM = Mg >> 7;
  const int tm = wg % nTM, tn = wg / nTM;
  const int rb = tm * 128, cb = tn * 128;
  const int NT = Kg >> 6;

  const int su0 = (g ^ (l16 & 7)) * 16;
  const int su1 = ((4 + g) ^ (l16 & 7)) * 16;
  const int offA = l16 * 128;
  const int offB0 = 16384 + (wn * 32 + l16) * 128;
  const int offB1 = offB0 + 2048;  // +16 cols

  const int r0 = tid >> 3;
  const int u8e = ((tid & 7) ^ (r0 & 7)) * 8;
  const unsigned short* sAa = A + (size_t)(rb + r0) * Kg + u8e;
  const unsigned short* sBb = BT + (size_t)(cb + r0) * Kg + u8e;
  const size_t rs32 = (size_t)Kg * 32;
  const int dstb = tid * 16;

  auto SA0 = [&](int t) { char* db = (char*)lds + ((t & 1) ? 32768 : 0);
    load16(sAa + (size_t)t * 64, db + dstb);
    load16(sAa + rs32 + (size_t)t * 64, db + 4096 + dstb); };
  auto SA1 = [&](int t) { char* db = (char*)lds + ((t & 1) ? 32768 : 0);
    load16(sAa + 2 * rs32 + (size_t)t * 64, db + 8192 + dstb);
    load16(sAa + 3 * rs32 + (size_t)t * 64, db + 12288 + dstb); };
  auto SB = [&](int t) { char* db = (char*)lds + ((t & 1) ? 32768 : 0) + 16384;
#pragma unroll
    for (int c = 0; c < 4; ++c)
      load16(sBb + c * rs32 + (size_t)t * 64, db + c * 4096 + dstb); };

  SA0(0); SA1(0); SB(0); SA0(1); SB(1);
  asm volatile("s_waitcnt vmcnt(6)" ::: "memory");
  __builtin_amdgcn_s_barrier();

  f32x4 acc[8][2] = {};
  bf16x8 a[4][2], b[2][2];

  for (int t = 0; t < NT; ++t) {
    const char* bs = (const char*)lds + ((t & 1) ? 32768 : 0);
    // ---- P1: read A rows 0-63 + both B groups; stage A1(t+1)
#pragma unroll
    for (int mf = 0; mf < 4; ++mf) {
      a[mf][0] = *(const bf16x8*)(bs + offA + mf * 2048 + su0);
      a[mf][1] = *(const bf16x8*)(bs + offA + mf * 2048 + su1);
    }
    b[0][0] = *(const bf16x8*)(bs + offB0 + su0);
    b[0][1] = *(const bf16x8*)(bs + offB0 + su1);
    b[1][0] = *(const bf16x8*)(bs + offB1 + su0);
    b[1][1] = *(const bf16x8*)(bs + offB1 + su1);
    if (t + 1 < NT) SA1(t + 1);
    asm volatile("s_waitcnt lgkmcnt(8)" ::: "memory");
    __builtin_amdgcn_s_barrier();
    asm volatile("s_waitcnt lgkmcnt(0)" ::: "memory");
    __builtin_amdgcn_s_setprio(1);
#pragma unroll
    for (int mf = 0; mf < 4; ++mf)
#pragma unroll
      for (int nf = 0; nf < 2; ++nf)
#pragma unroll
        for (int kh = 0; kh < 2; ++kh)
          acc[mf][nf] = mfma16(a[mf][kh], b[nf][kh], acc[mf][nf]);
    __builtin_amdgcn_s_setprio(0);
    // RACE FIX: vmcnt before barrier (cross-wave A1(t) visibility).
    if (t == NT - 1) asm volatile("s_waitcnt vmcnt(0)" ::: "memory");
    else             asm volatile("s_waitcnt vmcnt(8)" ::: "memory");
    __builtin_amdgcn_s_barrier();
    // ---- P2: read A rows 64-127; stage A0/B(t+2)
#pragma unroll
    for (int mf = 0; mf < 4; ++mf) {
      a[mf][0] = *(const bf16x8*)(bs + offA + (mf + 4) * 2048 + su0);
      a[mf][1] = *(const bf16x8*)(bs + offA + (mf + 4) * 2048 + su1);
    }
    if (t + 2 < NT) { SA0(t + 2); SB(t + 2); }
    __builtin_amdgcn_s_barrier();
    asm volatile("s_waitcnt lgkmcnt(0)" ::: "memory");
    __builtin_amdgcn_s_setprio(1);
#pragma unroll
    for (int mf = 0; mf < 4; ++mf)
#pragma unroll
      for (int nf = 0; nf < 2; ++nf)
#pragma unroll
        for (int kh = 0; kh < 2; ++kh)
          acc[mf + 4][nf] = mfma16(a[mf][kh], b[nf][kh], acc[mf + 4][nf]);
    __builtin_amdgcn_s_setprio(0);
    if (t + 2 < NT)      asm volatile("s_waitcnt vmcnt(8)" ::: "memory");
    else if (t + 1 < NT) asm volatile("s_waitcnt vmcnt(2)" ::: "memory");
    __builtin_amdgcn_s_barrier();
  }

  // ---- epilogue: f32 + bias
  const int crow0 = rb + g * 4;
  const int ccol0 = cb + wn * 32 + l16;
  const float bv0 = bias[ccol0];
  const float bv1 = bias[ccol0 + 16];
#pragma unroll
  for (int mf = 0; mf < 8; ++mf)
#pragma unroll
    for (int r = 0; r < 4; ++r) {
      int row = crow0 + mf * 16 + r;
      float* p = Cout + (size_t)row * Ng + ccol0;
      p[0] = acc[mf][0][r] + bv0;
      p[16] = acc[mf][1][r] + bv1;
    }
}

// ----------------------------------------------------------- flash attention
DEV void stage_kv(const unsigned short* __restrict__ qkv,
                  const unsigned short* __restrict__ vt,
                  unsigned char* lds, int bS, int bh64, int hoff, int kvb, int buf, int tid) {
#pragma unroll
  for (int c = 0; c < 2; ++c) {
    int p = c * 256 + tid;
    int row = p >> 3, k8 = (p & 7) ^ (row & 7);
    load16(qkv + (size_t)(bS + kvb + row) * N3_ + 2048 + hoff + 8 * k8,
           lds + buf * 8192 + p * 16);
    load16(vt + (size_t)(bh64 + row) * S_ + kvb + 8 * k8,
           lds + 16384 + buf * 8192 + p * 16);
  }
}

__global__ __launch_bounds__(256, 3) void attn_kernel(const unsigned short* __restrict__ qkv,
                                                      const unsigned short* __restrict__ vt,
                                                      unsigned short* __restrict__ ao) {
  __shared__ __align__(16) unsigned char lds[49152];
  const int tid = threadIdx.x;
  const int lane = tid & 63, wv = tid >> 6;
  const int g = lane >> 4, l16 = lane & 15;
  const int bid = blockIdx.x;
  const int qi = 15 - (bid >> 6);
  const int t6 = bid & 63;
  const int bh = ((t6 & 7) << 3) | (t6 >> 3);
  const int b = bh >> 5, h = bh & 31;
  const int qbase = qi * 128;
  const int srow0 = qbase + wv * 32;
  const int bS = b * S_, bh64 = bh * 64, hoff = h * 64;

  bf16x8 qf[2][2];
#pragma unroll
  for (int m = 0; m < 2; ++m)
#pragma unroll
    for (int kt = 0; kt < 2; ++kt)
      qf[m][kt] = *(const bf16x8*)(qkv + (size_t)(bS + srow0 + m * 16 + l16) * N3_ +
                                   hoff + kt * 32 + g * 8);

  float mrun[2] = {-INFINITY, -INFINITY}, lrun[2] = {0.f, 0.f};
  f32x4 o[2][4] = {};
  unsigned char* pw = lds + 32768 + wv * 4096;

  const int nkv = (qbase + 128) >> 6;
  stage_kv(qkv, vt, lds, bS, bh64, hoff, 0, 0, tid);
  __syncthreads();

  for (int kb = 0; kb < nkv; ++kb) {
    const int cur = kb & 1;
    if (kb + 1 < nkv) stage_kv(qkv, vt, lds, bS, bh64, hoff, (kb + 1) << 6, cur ^ 1, tid);
    const int kvb = kb << 6;
    if (kvb <= srow0 + 31) {
      const unsigned char* kbuf = lds + cur * 8192;
      const unsigned char* vbuf = lds + 16384 + cur * 8192;

      f32x4 sc[2][4];
#pragma unroll
      for (int n = 0; n < 4; ++n) {
        int row = n * 16 + l16;
        bf16x8 kf0 = *(const bf16x8*)(kbuf + (row * 8 + ((g + 0) ^ (row & 7))) * 16);
        bf16x8 kf1 = *(const bf16x8*)(kbuf + (row * 8 + ((g + 4) ^ (row & 7))) * 16);
#pragma unroll
        for (int m = 0; m < 2; ++m) {
          f32x4 z = {};
          z = mfma16(kf0, qf[m][0], z);
          z = mfma16(kf1, qf[m][1], z);
          sc[m][n] = z;
        }
      }

      const bool boundary = (kvb + 63 > srow0);
#pragma unroll
      for (int m = 0; m < 2; ++m) {
        const int qrow = srow0 + m * 16 + l16;
        if (boundary) {
#pragma unroll
          for (int n = 0; n < 4; ++n)
#pragma unroll
            for (int r = 0; r < 4; ++r) {
              int k = kvb + n * 16 + g * 4 + r;
              if (k > qrow) sc[m][n][r] = -INFINITY;
            }
        }
        float mx = fmaxf(fmaxf(sc[m][0][0], sc[m][0][1]), fmaxf(sc[m][0][2], sc[m][0][3]));
#pragma unroll
        for (int n = 1; n < 4; ++n)
          mx = fmaxf(mx, fmaxf(fmaxf(sc[m][n][0], sc[m][n][1]), fmaxf(sc[m][n][2], sc[m][n][3])));
        mx = fmaxf(mx, __shfl_xor(mx, 16));
        mx = fmaxf(mx, __shfl_xor(mx, 32));
        float pm = mx * 0.125f;
        if (!__all(pm <= mrun[m] + 8.0f)) {
          float mn = fmaxf(mrun[m], pm);
          float al = exp2f((mrun[m] - mn) * 1.44269504f);
          mrun[m] = mn; lrun[m] *= al;
#pragma unroll
          for (int d = 0; d < 4; ++d) o[m][d] *= al;
        }
        const float mt = mrun[m] * 1.44269504f;
        float p[4][4]; float rs = 0.f;
#pragma unroll
        for (int n = 0; n < 4; ++n)
#pragma unroll
          for (int r = 0; r < 4; ++r) {
            p[n][r] = exp2f(fmaf(sc[m][n][r], 0.18033688011112042f, -mt));
            rs += p[n][r];
          }
        rs += __shfl_xor(rs, 16);
        rs += __shfl_xor(rs, 32);
        lrun[m] += rs;
#pragma unroll
        for (int n = 0; n < 4; ++n) {
          unsigned lo, hi;
          asm("v_cvt_pk_bf16_f32 %0, %1, %2" : "=v"(lo) : "v"(p[n][0]), "v"(p[n][1]));
          asm("v_cvt_pk_bf16_f32 %0, %1, %2" : "=v"(hi) : "v"(p[n][2]), "v"(p[n][3]));
          int su = (n * 4 + g) ^ ((l16 & 7) << 1);
          u32x2 wq; wq[0] = lo; wq[1] = hi;
          *(u32x2*)(pw + ((m * 16 + l16) * 16 + su) * 8) = wq;
        }
      }

      bf16x8 pf[2][2];
#pragma unroll
      for (int m = 0; m < 2; ++m)
#pragma unroll
        for (int kt = 0; kt < 2; ++kt) {
          int su = (kt * 8 + g * 2) ^ ((l16 & 7) << 1);
          pf[m][kt] = *(const bf16x8*)(pw + ((m * 16 + l16) * 16 + su) * 8);
        }
#pragma unroll
      for (int dblk = 0; dblk < 4; ++dblk) {
        int row = dblk * 16 + l16;
        bf16x8 vf0 = *(const bf16x8*)(vbuf + (row * 8 + ((g + 0) ^ (row & 7))) * 16);
        bf16x8 vf1 = *(const bf16x8*)(vbuf + (row * 8 + ((g + 4) ^ (row & 7))) * 16);
#pragma unroll
        for (int m = 0; m < 2; ++m) {
          o[m][dblk] = mfma16(vf0, pf[m][0], o[m][dblk]);
          o[m][dblk] = mfma16(vf1, pf[m][1], o[m][dblk]);
        }
      }
    }
    __syncthreads();
  }

#pragma unroll
  for (int m = 0; m < 2; ++m) {
    float inv = 1.0f / lrun[m];
    int q = srow0 + m * 16 + l16;
#pragma unroll
    for (int dblk = 0; dblk < 4; ++dblk) {
      u16x4 ov;
#pragma unroll
      for (int r = 0; r < 4; ++r) ov[r] = f2bf(o[m][dblk][r] * inv);
      *(u16x4*)(ao + (size_t)(bS + q) * D_ + hoff + dblk * 16 + g * 4) = ov;
    }
  }
}

// ---------------------------------------------------------------------- launch
extern "C" void kernel_launch(void* const* d_in, const int* in_sizes, int n_in,
                              void* d_out, int out_size, void* d_ws, size_t ws_size,
                              hipStream_t stream) {
  const float* x = (const float*)d_in[0];
  const float* Wqkv = (const float*)d_in[1];
  const float* bqkv = (const float*)d_in[2];
  const float* Wout = (const float*)d_in[3];
  const float* bout = (const float*)d_in[4];
  float* out = (float*)d_out;

  char* ws = (char*)d_ws;
  unsigned short* Xb = (unsigned short*)(ws + 0);                  // 16 MiB (reused as AO)
  unsigned short* Wqkvt = (unsigned short*)(ws + 16777216);        // 24 MiB
  unsigned short* Woutt = (unsigned short*)(ws + 41943040);        // 8 MiB
  unsigned short* QKVb = (unsigned short*)(ws + 50331648);         // 48 MiB
  unsigned short* Vt = (unsigned short*)(ws + 100663296);          // 16 MiB
  unsigned short* AO = Xb;  // Xb is dead after gemm1

  cvt_bf16<<<4096, 256, 0, stream>>>(x, Xb, M_ * D_);
  transpose_bf16<<<dim3(192, 64), 256, 0, stream>>>(Wqkv, Wqkvt, 2048, 6144);
  transpose_bf16<<<dim3(64, 64), 256, 0, stream>>>(Wout, Woutt, 2048, 2048);
  gemm_qkv<<<1024, 256, 0, stream>>>(Xb, Wqkvt, bqkv, QKVb, Vt, M_, N3_, D_);
  attn_kernel<<<1024, 256, 0, stream>>>(QKVb, Vt, AO);
  gemm_out<<<512, 256, 0, stream>>>(AO, Woutt, bout, out, M_, D_, D_);
}